// Round 17
// baseline (759.397 us; speedup 1.0000x reference)
//
#include <hip/hip_runtime.h>
#include <math.h>
#include <float.h>

#define Bb 8
#define Nn 2048
#define Ee 256
#define Hh 8
#define NB 3
#define KK 32
#define DH 32
#define QKV 768
#define FF 512
#define OUTPTS 1024

#define CEXP 0.25509667991878083f   // (1/sqrt(32)) * log2(e)

typedef __bf16 bf16x8 __attribute__((ext_vector_type(8)));
typedef __bf16 bf16x4 __attribute__((ext_vector_type(4)));
typedef float f32x4 __attribute__((ext_vector_type(4)));
typedef float f32x16 __attribute__((ext_vector_type(16)));
typedef unsigned u32x2 __attribute__((ext_vector_type(2)));

#if __has_builtin(__builtin_amdgcn_exp2f)
#define EXP2(x) __builtin_amdgcn_exp2f(x)
#else
#define EXP2(x) exp2f(x)
#endif

static __device__ __forceinline__ float geluf(float v) {
    return 0.5f * v * (1.0f + erff(v * 0.70710678118654752f));
}
static __device__ __forceinline__ float eluf(float v) {
    return v > 0.0f ? v : expm1f(v);
}
static __device__ __forceinline__ unsigned pkbf(float a, float b) {
    union { __bf16 h[2]; unsigned u; } t;
    t.h[0] = (__bf16)a; t.h[1] = (__bf16)b;
    return t.u;
}
// (a', b') halves swap: a' = [b.hi->lo || a.hi], b' = [b.lo || a.lo->hi]
static __device__ __forceinline__ void swap32(unsigned a, unsigned b, unsigned& outA, unsigned& outB, int hi) {
#if __has_builtin(__builtin_amdgcn_permlane32_swap)
    u32x2 r = __builtin_amdgcn_permlane32_swap(a, b, false, false);
    outA = r[0]; outB = r[1];
#else
    unsigned ax = (unsigned)__shfl_xor((int)a, 32, 64);
    unsigned bx = (unsigned)__shfl_xor((int)b, 32, 64);
    outB = hi ? ax : b;
    outA = hi ? a : bx;
#endif
}

// async global -> LDS, 16 bytes per lane (dest must be lane-linear: base + 16*lane)
#if __has_builtin(__builtin_amdgcn_global_load_lds)
#define HAVE_GLOAD_LDS 1
static __device__ __forceinline__ void gl_lds16(const __bf16* g, __bf16* l) {
    __builtin_amdgcn_global_load_lds(
        (const __attribute__((address_space(1))) unsigned*)g,
        (__attribute__((address_space(3))) unsigned*)l, 16, 0, 0);
}
#else
#define HAVE_GLOAD_LDS 0
#endif

// ---------------- pack x -> (x,y,z,|x|^2) ----------------
__global__ __launch_bounds__(256) void k_xp(const float* __restrict__ x, float4* __restrict__ xp) {
    int i = blockIdx.x * 256 + threadIdx.x;
    if (i < Bb * Nn) {
        float a = x[i * 3], b = x[i * 3 + 1], c = x[i * 3 + 2];
        xp[i] = make_float4(a, b, c, a * a + b * b + c * c);
    }
}

// ---------------- KNN: wave-per-query, ballot radix-select (x4-packed, tree-reduced counts) ----------------
__global__ __launch_bounds__(256) void k_knn(const float4* __restrict__ xp,
                                             int* __restrict__ idx) {
    int q = blockIdx.x * 4 + (threadIdx.x >> 6);
    int lane = threadIdx.x & 63;
    int b = q >> 11, n = q & (Nn - 1);
    const float4* xb = xp + (size_t)b * Nn;
    float4 qv = xb[n];
    float xn0 = qv.x, xn1 = qv.y, xn2 = qv.z, sqn = qv.w;

    unsigned cand[32];
#pragma unroll
    for (int c = 0; c < 32; ++c) {
        int m = lane + 64 * c;
        float4 v = xb[m];
        float t = xn0 * v.x;
        t = fmaf(xn1, v.y, t);
        t = fmaf(xn2, v.z, t);
        float d = (sqn + v.w) - 2.0f * t;
        unsigned fb = __float_as_uint(d);
        cand[c] = (fb & 0x80000000u) ? ~fb : (fb | 0x80000000u);   // monotonic total order
    }

    unsigned prefix = 0u;
    for (int bit = 31; bit >= 0; --bit) {
        unsigned t = prefix | (1u << bit);
        int p[32];
#pragma unroll
        for (int c = 0; c < 32; ++c)
            p[c] = (int)__popcll(__ballot(cand[c] < t));
        // explicit binary tree: depth 5, no serial SALU chain
        int s0 = ((p[0] + p[1]) + (p[2] + p[3])) + ((p[4] + p[5]) + (p[6] + p[7]));
        int s1 = ((p[8] + p[9]) + (p[10] + p[11])) + ((p[12] + p[13]) + (p[14] + p[15]));
        int s2 = ((p[16] + p[17]) + (p[18] + p[19])) + ((p[20] + p[21]) + (p[22] + p[23]));
        int s3 = ((p[24] + p[25]) + (p[26] + p[27])) + ((p[28] + p[29]) + (p[30] + p[31]));
        int cnt = (s0 + s1) + (s2 + s3);
        if (cnt < KK) prefix = t;
    }

    unsigned long long lmask = (1ULL << lane) - 1ULL;
    int base = 0;
#pragma unroll
    for (int c = 0; c < 32; ++c) {
        bool sel = cand[c] < prefix;
        unsigned long long mk = __ballot(sel);
        int pos = base + (int)__popcll(mk & lmask);
        if (sel) idx[(size_t)q * KK + pos] = lane + 64 * c;
        base += (int)__popcll(mk);
    }
    for (int c = 0; c < 32 && base < KK; ++c) {
        bool eq = (cand[c] == prefix);
        unsigned long long mk = __ballot(eq);
        int pos = base + (int)__popcll(mk & lmask);
        if (eq && pos < KK) idx[(size_t)q * KK + pos] = lane + 64 * c;
        base += (int)__popcll(mk);
    }
}

// ---------------- feat @ W1 + b1 ----------------
__global__ __launch_bounds__(256) void k_h1(const float* __restrict__ x, const int* __restrict__ idx,
                                            const float* __restrict__ W1, const float* __restrict__ b1,
                                            float* __restrict__ h1) {
    int t = blockIdx.x * 256 + threadIdx.x;   // < B*N*K
    if (t >= Bb * Nn * KK) return;
    int bn = t / KK;
    int b = bn / Nn, n = bn % Nn;
    int j = idx[t];
    const float* xb = x + (size_t)b * Nn * 3;
    float xn0 = xb[n * 3], xn1 = xb[n * 3 + 1], xn2 = xb[n * 3 + 2];
    float f3 = xn0 - xb[j * 3], f4 = xn1 - xb[j * 3 + 1], f5 = xn2 - xb[j * 3 + 2];
    float* o = h1 + (size_t)t * 6;
#pragma unroll
    for (int c = 0; c < 6; ++c) {
        o[c] = b1[c] + xn0 * W1[0 * 6 + c] + xn1 * W1[1 * 6 + c] + xn2 * W1[2 * 6 + c]
             + f3 * W1[3 * 6 + c] + f4 * W1[4 * 6 + c] + f5 * W1[5 * 6 + c];
    }
}

// ---------------- two-stage BN stats, deterministic, coalesced ----------------
__global__ __launch_bounds__(256) void k_stats6_part(const float* __restrict__ v, int R, int nblk,
                                                     double* __restrict__ part) {
    int blk = blockIdx.x, tid = threadIdx.x;
    int rows = R / nblk;
    int r0 = blk * rows;
    double s[6] = {0, 0, 0, 0, 0, 0}, s2[6] = {0, 0, 0, 0, 0, 0};
    for (int r = r0 + tid; r < r0 + rows; r += 256) {
        const float* p = v + (size_t)r * 6;
#pragma unroll
        for (int c = 0; c < 6; ++c) { double t = p[c]; s[c] += t; s2[c] += t * t; }
    }
    __shared__ double sh[256][12];
#pragma unroll
    for (int c = 0; c < 6; ++c) { sh[tid][c] = s[c]; sh[tid][6 + c] = s2[c]; }
    __syncthreads();
    for (int st = 128; st > 0; st >>= 1) {
        if (tid < st) {
#pragma unroll
            for (int q = 0; q < 12; ++q) sh[tid][q] += sh[tid + st][q];
        }
        __syncthreads();
    }
    if (tid < 12) part[(size_t)blk * 12 + tid] = sh[0][tid];
}

// parallel finalizer: 192 threads = 12 stats x 16 groups
__global__ __launch_bounds__(256) void k_stats6_fin(const double* __restrict__ part, int nblk, int R,
                                                    float* __restrict__ mean, float* __restrict__ rstd) {
    __shared__ double sh[16][12];
    int t = threadIdx.x;
    if (t < 192) {
        int q = t % 12, g = t / 12;          // g < 16
        double s = 0.0;
        for (int b = g; b < nblk; b += 16) s += part[(size_t)b * 12 + q];
        sh[g][q] = s;
    }
    __syncthreads();
    if (t < 12) {
        double s = 0.0;
#pragma unroll
        for (int g = 0; g < 16; ++g) s += sh[g][t];
        sh[0][t] = s;
    }
    __syncthreads();
    if (t < 6) {
        double mu = sh[0][t] / R;
        double var = sh[0][6 + t] / R - mu * mu;
        mean[t] = (float)mu;
        rstd[t] = (float)(1.0 / sqrt(var + 1e-5));
    }
}

__global__ __launch_bounds__(256) void k_stats256_part(const float* __restrict__ v, int R, int nblk,
                                                       double* __restrict__ part) {
    int blk = blockIdx.x, c = threadIdx.x;
    int rows = R / nblk;
    int r0 = blk * rows;
    double s = 0.0, s2 = 0.0;
    for (int r = r0; r < r0 + rows; ++r) {
        double t = v[(size_t)r * Ee + c];
        s += t; s2 += t * t;
    }
    part[(size_t)blk * (2 * Ee) + c] = s;
    part[(size_t)blk * (2 * Ee) + Ee + c] = s2;
}

// 4 independent accumulators break the serial dependent-load chain
__global__ __launch_bounds__(256) void k_stats256_fin(const double* __restrict__ part, int nblk, int R,
                                                      float* __restrict__ mean, float* __restrict__ rstd) {
    int c = threadIdx.x;
    double s0 = 0.0, s1 = 0.0, s2a = 0.0, s3 = 0.0;
    double t0 = 0.0, t1 = 0.0, t2 = 0.0, t3 = 0.0;
    for (int b = 0; b < nblk; b += 4) {
        s0 += part[(size_t)b * (2 * Ee) + c];
        s1 += part[(size_t)(b + 1) * (2 * Ee) + c];
        s2a += part[(size_t)(b + 2) * (2 * Ee) + c];
        s3 += part[(size_t)(b + 3) * (2 * Ee) + c];
        t0 += part[(size_t)b * (2 * Ee) + Ee + c];
        t1 += part[(size_t)(b + 1) * (2 * Ee) + Ee + c];
        t2 += part[(size_t)(b + 2) * (2 * Ee) + Ee + c];
        t3 += part[(size_t)(b + 3) * (2 * Ee) + Ee + c];
    }
    double s = (s0 + s1) + (s2a + s3);
    double s2 = (t0 + t1) + (t2 + t3);
    double mu = s / R;
    double var = s2 / R - mu * mu;
    mean[c] = (float)mu;
    rstd[c] = (float)(1.0 / sqrt(var + 1e-5));
}

// ---------------- BN1+ELU, max over K, @W2+b2 ----------------
__global__ __launch_bounds__(256) void k_maxh2(const float* __restrict__ h1,
                                               const float* __restrict__ mean1, const float* __restrict__ rstd1,
                                               const float* __restrict__ g1, const float* __restrict__ be1,
                                               const float* __restrict__ W2, const float* __restrict__ b2,
                                               float* __restrict__ x0) {
    int bn = blockIdx.x;
    int t = threadIdx.x;
    __shared__ float hval[KK][6];
    __shared__ float hmax[6];
    if (t < KK * 6) {
        int k = t / 6, c = t % 6;
        float v = h1[((size_t)bn * KK + k) * 6 + c];
        v = (v - mean1[c]) * rstd1[c] * g1[c] + be1[c];
        hval[k][c] = eluf(v);
    }
    __syncthreads();
    if (t < 6) {
        float m = -FLT_MAX;
        for (int k = 0; k < KK; ++k) m = fmaxf(m, hval[k][t]);
        hmax[t] = m;
    }
    __syncthreads();
    float s = b2[t];
#pragma unroll
    for (int i = 0; i < 6; ++i) s += hmax[i] * W2[i * Ee + t];
    x0[(size_t)bn * Ee + t] = s;
}

// ---------------- fused BN2-apply + layer-0 LN (wave per row) ----------------
__global__ __launch_bounds__(256) void k_bnln(float* __restrict__ X,
                                              const float* __restrict__ mean2, const float* __restrict__ rstd2,
                                              const float* __restrict__ g2, const float* __restrict__ be2,
                                              const float* __restrict__ g, const float* __restrict__ b,
                                              __bf16* __restrict__ Yb) {
    int row = blockIdx.x * 4 + (threadIdx.x >> 6);
    int lane = threadIdx.x & 63;
    int c0 = lane * 4;
    float4 v = *(const float4*)(X + (size_t)row * Ee + c0);
    // BN + ELU (channel = c0+j)
    v.x = eluf((v.x - mean2[c0 + 0]) * rstd2[c0 + 0] * g2[c0 + 0] + be2[c0 + 0]);
    v.y = eluf((v.y - mean2[c0 + 1]) * rstd2[c0 + 1] * g2[c0 + 1] + be2[c0 + 1]);
    v.z = eluf((v.z - mean2[c0 + 2]) * rstd2[c0 + 2] * g2[c0 + 2] + be2[c0 + 2]);
    v.w = eluf((v.w - mean2[c0 + 3]) * rstd2[c0 + 3] * g2[c0 + 3] + be2[c0 + 3]);
    *(float4*)(X + (size_t)row * Ee + c0) = v;
    // LN
    float s = v.x + v.y + v.z + v.w;
#pragma unroll
    for (int off = 32; off; off >>= 1) s += __shfl_xor(s, off, 64);
    float mu = s * (1.0f / Ee);
    float d0 = v.x - mu, d1 = v.y - mu, d2 = v.z - mu, d3 = v.w - mu;
    float s2 = d0 * d0 + d1 * d1 + d2 * d2 + d3 * d3;
#pragma unroll
    for (int off = 32; off; off >>= 1) s2 += __shfl_xor(s2, off, 64);
    float rstd = 1.0f / sqrtf(s2 * (1.0f / Ee) + 1e-5f);
    float4 gv = *(const float4*)(g + c0);
    float4 bv = *(const float4*)(b + c0);
    bf16x4 o;
    o[0] = (__bf16)(gv.x * d0 * rstd + bv.x);
    o[1] = (__bf16)(gv.y * d1 * rstd + bv.y);
    o[2] = (__bf16)(gv.z * d2 * rstd + bv.z);
    o[3] = (__bf16)(gv.w * d3 * rstd + bv.w);
    *(bf16x4*)(Yb + (size_t)row * Ee + c0) = o;
}

// ---------------- LayerNorm -> bf16 (one wave per row of 256) ----------------
__global__ __launch_bounds__(256) void k_lnb(const float* __restrict__ X,
                                             const float* __restrict__ g, const float* __restrict__ b,
                                             __bf16* __restrict__ Yb) {
    int row = blockIdx.x * 4 + (threadIdx.x >> 6);
    int lane = threadIdx.x & 63;
    float4 v = *(const float4*)(X + (size_t)row * Ee + lane * 4);
    float s = v.x + v.y + v.z + v.w;
#pragma unroll
    for (int off = 32; off; off >>= 1) s += __shfl_xor(s, off, 64);
    float mu = s * (1.0f / Ee);
    float d0 = v.x - mu, d1 = v.y - mu, d2 = v.z - mu, d3 = v.w - mu;
    float s2 = d0 * d0 + d1 * d1 + d2 * d2 + d3 * d3;
#pragma unroll
    for (int off = 32; off; off >>= 1) s2 += __shfl_xor(s2, off, 64);
    float rstd = 1.0f / sqrtf(s2 * (1.0f / Ee) + 1e-5f);
    float4 gv = *(const float4*)(g + lane * 4);
    float4 bv = *(const float4*)(b + lane * 4);
    bf16x4 o;
    o[0] = (__bf16)(gv.x * d0 * rstd + bv.x);
    o[1] = (__bf16)(gv.y * d1 * rstd + bv.y);
    o[2] = (__bf16)(gv.z * d2 * rstd + bv.z);
    o[3] = (__bf16)(gv.w * d3 * rstd + bv.w);
    *(bf16x4*)(Yb + (size_t)row * Ee + lane * 4) = o;
}

// ---------------- fused weight transpose + bf16 convert for all 4 weight sets ----------------
__global__ __launch_bounds__(256) void k_wtall(const float* __restrict__ attn_w, const float* __restrict__ out_w,
                                               const float* __restrict__ ff1_w, const float* __restrict__ ff2_w,
                                               __bf16* __restrict__ attn_wt, __bf16* __restrict__ out_wt,
                                               __bf16* __restrict__ ff1_wt, __bf16* __restrict__ ff2_wt) {
    int bid = blockIdx.x;
    const float* w; __bf16* wt; int K, N, n0, k0;
    if (bid < 144) {           // attn: 12 x 4 x 3
        int r = bid; int z = r / 48; r %= 48;
        K = Ee; N = QKV; n0 = (r % 12) * 64; k0 = (r / 12) * 64;
        w = attn_w + (size_t)z * K * N; wt = attn_wt + (size_t)z * K * N;
    } else if (bid < 192) {    // out: 4 x 4 x 3
        int r = bid - 144; int z = r / 16; r %= 16;
        K = Ee; N = Ee; n0 = (r % 4) * 64; k0 = (r / 4) * 64;
        w = out_w + (size_t)z * K * N; wt = out_wt + (size_t)z * K * N;
    } else if (bid < 288) {    // ff1: 8 x 4 x 3
        int r = bid - 192; int z = r / 32; r %= 32;
        K = Ee; N = FF; n0 = (r % 8) * 64; k0 = (r / 8) * 64;
        w = ff1_w + (size_t)z * K * N; wt = ff1_wt + (size_t)z * K * N;
    } else {                   // ff2: 4 x 8 x 3
        int r = bid - 288; int z = r / 32; r %= 32;
        K = FF; N = Ee; n0 = (r % 4) * 64; k0 = (r / 4) * 64;
        w = ff2_w + (size_t)z * K * N; wt = ff2_wt + (size_t)z * K * N;
    }
    __shared__ float L[64][65];
    int t = threadIdx.x;
    int r = t >> 4, c4 = (t & 15) * 4;
#pragma unroll
    for (int j = 0; j < 4; ++j) {
        float4 v = *(const float4*)(w + (size_t)(k0 + r + j * 16) * N + n0 + c4);
        L[r + j * 16][c4 + 0] = v.x; L[r + j * 16][c4 + 1] = v.y;
        L[r + j * 16][c4 + 2] = v.z; L[r + j * 16][c4 + 3] = v.w;
    }
    __syncthreads();
#pragma unroll
    for (int j = 0; j < 4; ++j) {
        int nn = r + j * 16;
        bf16x4 o;
        o[0] = (__bf16)L[c4 + 0][nn]; o[1] = (__bf16)L[c4 + 1][nn];
        o[2] = (__bf16)L[c4 + 2][nn]; o[3] = (__bf16)L[c4 + 3][nn];
        *(bf16x4*)(wt + (size_t)(n0 + nn) * K + k0 + c4) = o;
    }
}

// ---------------- bf16 MFMA GEMM, 64x128 tile ----------------
// OUTM: 0=f32 1=bf16 ; RESM: 0=none 1=bf16 2=f32 ; ACT: 0=none 1=gelu
// QKVM=1: q-cols (<Ee) scaled by CEXP -> qkvb; K-cols -> kp[b][h][key][d] (per-head packed);
//         V-cols -> vt[b][h][key/32][d][key%32]; K/V NOT written to qkvb (attn reads Kp/Vt).
template<int OUTM, int RESM, int ACT, int QKVM>
__global__ __launch_bounds__(256) void k_mgemm(const __bf16* __restrict__ Ain,
                                               const __bf16* __restrict__ Wt,
                                               const float* __restrict__ bias,
                                               const void* __restrict__ res,
                                               void* __restrict__ out,
                                               int Kd, int Nd,
                                               __bf16* __restrict__ kp,
                                               __bf16* __restrict__ vt) {
    __shared__ __bf16 As[64 * 32];
    __shared__ __bf16 Bs[128 * 32];
    int tid = threadIdx.x;
    int n0 = blockIdx.x * 128, m0 = blockIdx.y * 64;
    int wave = tid >> 6, lane = tid & 63;
    int wr = wave >> 1, wc = wave & 1;      // wave rows: wr*32, cols: wc*64
    int t = lane & 15, gg = lane >> 4;
    f32x4 acc[2][4];
#pragma unroll
    for (int m = 0; m < 2; ++m)
#pragma unroll
        for (int nn = 0; nn < 4; ++nn) acc[m][nn] = (f32x4){0.f, 0.f, 0.f, 0.f};
    int r0 = tid >> 2, g0 = tid & 3;        // rows 0..63, 8-col groups
    for (int kt = 0; kt < Kd; kt += 32) {
#if HAVE_GLOAD_LDS
        __syncthreads();          // prior iteration's frag reads complete before overwrite
        gl_lds16(Ain + (size_t)(m0 + r0) * Kd + kt + g0 * 8, &As[r0 * 32 + g0 * 8]);
        gl_lds16(Wt + (size_t)(n0 + r0) * Kd + kt + g0 * 8, &Bs[r0 * 32 + g0 * 8]);
        gl_lds16(Wt + (size_t)(n0 + 64 + r0) * Kd + kt + g0 * 8, &Bs[(64 + r0) * 32 + g0 * 8]);
        __syncthreads();          // drains vmcnt: LDS tiles ready
#else
        bf16x8 a0 = *(const bf16x8*)(Ain + (size_t)(m0 + r0) * Kd + kt + g0 * 8);
        bf16x8 w0 = *(const bf16x8*)(Wt + (size_t)(n0 + r0) * Kd + kt + g0 * 8);
        bf16x8 w1 = *(const bf16x8*)(Wt + (size_t)(n0 + 64 + r0) * Kd + kt + g0 * 8);
        __syncthreads();
        *(bf16x8*)&As[r0 * 32 + g0 * 8] = a0;
        *(bf16x8*)&Bs[r0 * 32 + g0 * 8] = w0;
        *(bf16x8*)&Bs[(64 + r0) * 32 + g0 * 8] = w1;
        __syncthreads();
#endif
        bf16x8 af[2], bfr[4];
#pragma unroll
        for (int m = 0; m < 2; ++m) af[m] = *(const bf16x8*)&As[(wr * 32 + m * 16 + t) * 32 + gg * 8];
#pragma unroll
        for (int nn = 0; nn < 4; ++nn) bfr[nn] = *(const bf16x8*)&Bs[(wc * 64 + nn * 16 + t) * 32 + gg * 8];
#pragma unroll
        for (int m = 0; m < 2; ++m)
#pragma unroll
            for (int nn = 0; nn < 4; ++nn)
                acc[m][nn] = __builtin_amdgcn_mfma_f32_16x16x32_bf16(af[m], bfr[nn], acc[m][nn], 0, 0, 0);
    }
#pragma unroll
    for (int m = 0; m < 2; ++m) {
#pragma unroll
        for (int nn = 0; nn < 4; ++nn) {
            int ocol = n0 + wc * 64 + nn * 16 + t;
            float bv = bias[ocol];
            float vv[4];
#pragma unroll
            for (int j = 0; j < 4; ++j) {
                int orow = m0 + wr * 32 + m * 16 + gg * 4 + j;
                float v = acc[m][nn][j] + bv;
                if (RESM == 1) v += (float)((const __bf16*)res)[(size_t)orow * Nd + ocol];
                if (RESM == 2) v += ((const float*)res)[(size_t)orow * Nd + ocol];
                if (ACT == 1) v = geluf(v);
                if (QKVM == 1 && ocol < Ee) v *= CEXP;   // pre-scale q for attn exp2
                vv[j] = v;
                if (!(QKVM == 1 && ocol >= Ee)) {        // K/V skip qkvb; go to Kp/Vt instead
                    if (OUTM == 0) ((float*)out)[(size_t)orow * Nd + ocol] = v;
                    else           ((__bf16*)out)[(size_t)orow * Nd + ocol] = (__bf16)v;
                }
            }
            if (QKVM == 1 && ocol >= Ee && ocol < 2 * Ee) {   // per-head packed K store
                int d = ocol - Ee;
                int h = d >> 5, dd = d & 31;
                int orow0 = m0 + wr * 32 + m * 16 + gg * 4;
                int bi = orow0 >> 11, n = orow0 & (Nn - 1);
                __bf16* kb = kp + (((size_t)(bi * Hh + h) * Nn + n) * DH + dd);
                kb[0] = (__bf16)vv[0]; kb[DH] = (__bf16)vv[1];
                kb[2 * DH] = (__bf16)vv[2]; kb[3 * DH] = (__bf16)vv[3];
            }
            if (QKVM == 1 && ocol >= 2 * Ee) {           // blocked-transpose V store
                int d = ocol - 2 * Ee;
                int h = d >> 5, dd = d & 31;
                int orow0 = m0 + wr * 32 + m * 16 + gg * 4;
                int bi = orow0 >> 11, n = orow0 & (Nn - 1);
                int kc = n >> 5, k5 = n & 31;
                bf16x4 o;
                o[0] = (__bf16)vv[0]; o[1] = (__bf16)vv[1];
                o[2] = (__bf16)vv[2]; o[3] = (__bf16)vv[3];
                *(bf16x4*)(vt + ((((size_t)(bi * Hh + h) * (Nn / 32) + kc) * DH + dd) << 5) + k5) = o;
            }
        }
    }
}

// ---------------- swapped-operand 32x32 MFMA flash attention: no LDS, no barriers ----------------
// Q (pre-scaled) from qkvb; K from per-head packed Kp; V from 32-key-blocked Vt.
__global__ __launch_bounds__(256) void k_attn(const __bf16* __restrict__ qkv,
                                              const __bf16* __restrict__ kp,
                                              const __bf16* __restrict__ vt,
                                              __bf16* __restrict__ obf) {
    int wgid = (blockIdx.x & 7) * 128 + (blockIdx.x >> 3);   // 1024 blocks, bijective
    int qg = wgid & 15;
    int bh = wgid >> 4;
    int h = bh & 7, b = bh >> 3;
    int wave = threadIdx.x >> 6, lane = threadIdx.x & 63;
    int l31 = lane & 31, hi = lane >> 5;
    int qb = qg * 128 + wave * 32;
    const size_t base = (size_t)b * Nn * QKV;

    const __bf16* qrow = qkv + base + (size_t)(qb + l31) * QKV + h * DH;
    bf16x8 qf0 = *(const bf16x8*)(qrow + hi * 8);
    bf16x8 qf1 = *(const bf16x8*)(qrow + 16 + hi * 8);

    const __bf16* kpb = kp + ((size_t)(b * Hh + h) * Nn + l31) * DH + hi * 8;   // + c0*DH per chunk
    const __bf16* vtb = vt + ((size_t)(b * Hh + h) * (Nn / 32)) * DH * 32 + l31 * 32 + hi * 8;

    f32x16 oacc = {0.f,0.f,0.f,0.f,0.f,0.f,0.f,0.f,0.f,0.f,0.f,0.f,0.f,0.f,0.f,0.f};
    float lsum = 0.0f;

    for (int c0 = 0; c0 < Nn; c0 += 32) {
        const __bf16* kr = kpb + (size_t)c0 * DH;
        bf16x8 kf0 = *(const bf16x8*)kr;           // K[c0+l31][d=hi*8..]
        bf16x8 kf1 = *(const bf16x8*)(kr + 16);    // K[c0+l31][d=16+hi*8..]

        f32x16 s = {0.f,0.f,0.f,0.f,0.f,0.f,0.f,0.f,0.f,0.f,0.f,0.f,0.f,0.f,0.f,0.f};
        s = __builtin_amdgcn_mfma_f32_32x32x16_bf16(kf0, qf0, s, 0, 0, 0);
        s = __builtin_amdgcn_mfma_f32_32x32x16_bf16(kf1, qf1, s, 0, 0, 0);
        // lane holds S^T[key=(reg&3)+8*(reg>>2)+4*hi][q=l31], already in log2 units

        float p[16];
#pragma unroll
        for (int i = 0; i < 16; ++i) p[i] = EXP2(s[i]);
        float s0 = (p[0] + p[1]) + (p[2] + p[3]);
        float s1 = (p[4] + p[5]) + (p[6] + p[7]);
        float s2r = (p[8] + p[9]) + (p[10] + p[11]);
        float s3 = (p[12] + p[13]) + (p[14] + p[15]);
        lsum += (s0 + s1) + (s2r + s3);

        unsigned d0 = pkbf(p[0], p[1]),  d1 = pkbf(p[2], p[3]);
        unsigned d2 = pkbf(p[4], p[5]),  d3 = pkbf(p[6], p[7]);
        unsigned d4 = pkbf(p[8], p[9]),  d5 = pkbf(p[10], p[11]);
        unsigned d6 = pkbf(p[12], p[13]), d7 = pkbf(p[14], p[15]);
        unsigned w0a, w0b, w1a, w1b, w2a, w2b, w3a, w3b;
        swap32(d2, d0, w2a, w0a, hi);
        swap32(d3, d1, w3a, w1a, hi);
        swap32(d6, d4, w2b, w0b, hi);
        swap32(d7, d5, w3b, w1b, hi);
        union { unsigned u[4]; bf16x8 v; } pa0, pa1;
        pa0.u[0] = w0a; pa0.u[1] = w1a; pa0.u[2] = w2a; pa0.u[3] = w3a;
        pa1.u[0] = w0b; pa1.u[1] = w1b; pa1.u[2] = w2b; pa1.u[3] = w3b;

        const __bf16* vp = vtb + (size_t)(c0 >> 5) * (DH * 32);
        bf16x8 vf0 = *(const bf16x8*)vp;           // V[key=hi*8+j][d=l31]
        bf16x8 vf1 = *(const bf16x8*)(vp + 16);    // V[key=16+hi*8+j][d=l31]

        oacc = __builtin_amdgcn_mfma_f32_32x32x16_bf16(pa0.v, vf0, oacc, 0, 0, 0);
        oacc = __builtin_amdgcn_mfma_f32_32x32x16_bf16(pa1.v, vf1, oacc, 0, 0, 0);
    }

    float ltot = lsum + __shfl_xor(lsum, 32, 64);
    float invl = 1.0f / ltot;     // valid for q = l31
#pragma unroll
    for (int reg = 0; reg < 16; ++reg) {
        int row = (reg & 3) + 8 * (reg >> 2) + 4 * hi;
        float iv = __shfl(invl, row, 64);
        obf[((size_t)(b * Nn + qb + row)) * Ee + h * DH + l31] = (__bf16)(oacc[reg] * iv);
    }
}

// ---------------- decoder ----------------
__global__ __launch_bounds__(256) void k_meanpart(const float* __restrict__ X, float* __restrict__ pm) {
    int chunk = blockIdx.x, b = blockIdx.y;
    int e = threadIdx.x;
    float s = 0.0f;
    for (int n = chunk * 256; n < chunk * 256 + 256; ++n)
        s += X[((size_t)b * Nn + n) * Ee + e];
    pm[(size_t)(b * 8 + chunk) * Ee + e] = s;
}
__global__ __launch_bounds__(256) void k_meanfin(const float* __restrict__ pm, float* __restrict__ m) {
    int i = blockIdx.x * 256 + threadIdx.x;
    int b = i >> 8, e = i & 255;
    float s = 0.0f;
    for (int c = 0; c < 8; ++c) s += pm[(size_t)(b * 8 + c) * Ee + e];
    m[i] = s * (1.0f / Nn);
}
__global__ __launch_bounds__(512) void k_dec1(const float* __restrict__ m, const float* __restrict__ w,
                                              const float* __restrict__ bias, float* __restrict__ t1) {
    int b = blockIdx.x, j = threadIdx.x;
    float s = bias[j];
    for (int i = 0; i < Ee; ++i) s += m[b * Ee + i] * w[i * FF + j];
    t1[b * FF + j] = geluf(s);
}
__global__ __launch_bounds__(256) void k_dec2(const float* __restrict__ t1, const float* __restrict__ w,
                                              const float* __restrict__ bias, float* __restrict__ out) {
    int i = blockIdx.x * 256 + threadIdx.x;
    int b = i / 3072, j = i % 3072;
    float s = bias[j];
    for (int k = 0; k < FF; ++k) s += t1[b * FF + k] * w[k * 3072 + j];
    out[i] = s;
}

extern "C" void kernel_launch(void* const* d_in, const int* in_sizes, int n_in,
                              void* d_out, int out_size, void* d_ws, size_t ws_size,
                              hipStream_t stream) {
    const float* x      = (const float*)d_in[0];
    const float* W1     = (const float*)d_in[1];
    const float* b1     = (const float*)d_in[2];
    const float* g1     = (const float*)d_in[3];
    const float* be1    = (const float*)d_in[4];
    const float* W2     = (const float*)d_in[5];
    const float* b2     = (const float*)d_in[6];
    const float* g2     = (const float*)d_in[7];
    const float* be2    = (const float*)d_in[8];
    const float* ln1_g  = (const float*)d_in[9];
    const float* ln1_b  = (const float*)d_in[10];
    const float* attn_w = (const float*)d_in[11];
    const float* attn_b = (const float*)d_in[12];
    const float* out_w  = (const float*)d_in[13];
    const float* out_b  = (const float*)d_in[14];
    const float* ln2_g  = (const float*)d_in[15];
    const float* ln2_b  = (const float*)d_in[16];
    const float* ff1_w  = (const float*)d_in[17];
    const float* ff1_b  = (const float*)d_in[18];
    const float* ff2_w  = (const float*)d_in[19];
    const float* ff2_b  = (const float*)d_in[20];
    const float* dec1_w = (const float*)d_in[21];
    const float* dec1_b = (const float*)d_in[22];
    const float* dec2_w = (const float*)d_in[23];
    const float* dec2_b = (const float*)d_in[24];
    (void)in_sizes; (void)n_in; (void)out_size; (void)ws_size;

    const size_t MN = (size_t)Bb * Nn * Ee;            // 16384*256

    float*  A    = (float*)d_ws;                       // xcur fp32
    __bf16* Ab   = (__bf16*)(A + MN);                  // hn bf16
    __bf16* qkvb = Ab + MN;                            // qkv bf16 (only q-cols written in steady state)
    __bf16* obf  = qkvb + (size_t)Bb * Nn * QKV;       // attn out bf16
    __bf16* ffb  = obf + MN;                           // ff intermediate bf16 (aliases Kp+Vt)
    __bf16* attn_wt = ffb + (size_t)Bb * Nn * FF;      // transposed bf16 weights
    __bf16* out_wt  = attn_wt + (size_t)NB * QKV * Ee;
    __bf16* ff1_wt  = out_wt + (size_t)NB * Ee * Ee;
    __bf16* ff2_wt  = ff1_wt + (size_t)NB * FF * Ee;
    float*  S       = (float*)(ff2_wt + (size_t)NB * Ee * FF);

    // Kp[b][h][key][d] and Vt32[b][h][key/32][d][key%32] alias ffb
    __bf16* Vt = ffb;
    __bf16* Kp = ffb + (size_t)Bb * Hh * Nn * DH;

    float* mean1 = S,      *rstd1 = S + 16;
    float* mean2 = S + 32, *rstd2 = S + 32 + Ee;
    float* pm    = S + 1024;
    float* mvec  = pm + 64 * Ee;
    float* t1    = mvec + Bb * Ee;
    double* part6   = (double*)(S + 32768);
    double* part256 = part6 + 512 * 12;
    float*  xpf     = (float*)(part256 + 64 * 512);    // packed x4: 16384 * 4 floats (256 KB)

    // ARPE scratch aliases qkvb (dead until first qkv GEMM)
    int*   idx = (int*)qkvb;
    float* h1  = (float*)(idx + (size_t)Bb * Nn * KK);

    // fused weight convert+transpose (independent of ARPE)
    k_wtall<<<384, 256, 0, stream>>>(attn_w, out_w, ff1_w, ff2_w,
                                     attn_wt, out_wt, ff1_wt, ff2_wt);

    k_xp  <<<(Bb * Nn + 255) / 256, 256, 0, stream>>>(x, (float4*)xpf);
    k_knn <<<Bb * Nn / 4, 256, 0, stream>>>((const float4*)xpf, idx);
    k_h1  <<<(Bb * Nn * KK) / 256, 256, 0, stream>>>(x, idx, W1, b1, h1);
    k_stats6_part<<<512, 256, 0, stream>>>(h1, Bb * Nn * KK, 512, part6);
    k_stats6_fin<<<1, 256, 0, stream>>>(part6, 512, Bb * Nn * KK, mean1, rstd1);
    k_maxh2<<<Bb * Nn, 256, 0, stream>>>(h1, mean1, rstd1, g1, be1, W2, b2, A);
    k_stats256_part<<<64, 256, 0, stream>>>(A, Bb * Nn, 64, part256);
    k_stats256_fin<<<1, 256, 0, stream>>>(part256, 64, Bb * Nn, mean2, rstd2);
    // fused BN2-apply + layer-0 LN
    k_bnln<<<Bb * Nn / 4, 256, 0, stream>>>(A, mean2, rstd2, g2, be2, ln1_g, ln1_b, Ab);

    const int M = Bb * Nn;
    for (int i = 0; i < NB; ++i) {
        if (i > 0)
            k_lnb<<<M / 4, 256, 0, stream>>>(A, ln1_g + i * Ee, ln1_b + i * Ee, Ab);
        k_mgemm<1, 0, 0, 1><<<dim3(QKV / 128, M / 64), 256, 0, stream>>>(
            Ab, attn_wt + (size_t)i * QKV * Ee, attn_b + i * QKV, nullptr, qkvb, Ee, QKV, Kp, Vt);
        k_attn<<<Bb * Hh * 16, 256, 0, stream>>>(qkvb, Kp, Vt, obf);
        k_mgemm<0, 1, 0, 0><<<dim3(Ee / 128, M / 64), 256, 0, stream>>>(
            obf, out_wt + (size_t)i * Ee * Ee, out_b + i * Ee, Ab, A, Ee, Ee, nullptr, nullptr);
        k_lnb<<<M / 4, 256, 0, stream>>>(A, ln2_g + i * Ee, ln2_b + i * Ee, Ab);
        k_mgemm<1, 0, 1, 0><<<dim3(FF / 128, M / 64), 256, 0, stream>>>(
            Ab, ff1_wt + (size_t)i * FF * Ee, ff1_b + i * FF, nullptr, ffb, Ee, FF, nullptr, nullptr);
        k_mgemm<0, 2, 0, 0><<<dim3(Ee / 128, M / 64), 256, 0, stream>>>(
            ffb, ff2_wt + (size_t)i * Ee * FF, ff2_b + i * Ee, A, A, FF, Ee, nullptr, nullptr);
    }

    k_meanpart<<<dim3(8, Bb), 256, 0, stream>>>(A, pm);
    k_meanfin<<<Bb, 256, 0, stream>>>(pm, mvec);
    k_dec1<<<Bb, FF, 0, stream>>>(mvec, dec1_w, dec1_b, t1);
    k_dec2<<<(Bb * OUTPTS * 3) / 256, 256, 0, stream>>>(t1, dec2_w, dec2_b, (float*)d_out);
}

// Round 18
// 731.192 us; speedup vs baseline: 1.0386x; 1.0386x over previous
//
#include <hip/hip_runtime.h>
#include <math.h>
#include <float.h>

#define Bb 8
#define Nn 2048
#define Ee 256
#define Hh 8
#define NB 3
#define KK 32
#define DH 32
#define QKV 768
#define FF 512
#define OUTPTS 1024

#define CEXP 0.25509667991878083f   // (1/sqrt(32)) * log2(e)

typedef __bf16 bf16x8 __attribute__((ext_vector_type(8)));
typedef __bf16 bf16x4 __attribute__((ext_vector_type(4)));
typedef float f32x4 __attribute__((ext_vector_type(4)));
typedef float f32x16 __attribute__((ext_vector_type(16)));
typedef unsigned u32x2 __attribute__((ext_vector_type(2)));

#if __has_builtin(__builtin_amdgcn_exp2f)
#define EXP2(x) __builtin_amdgcn_exp2f(x)
#else
#define EXP2(x) exp2f(x)
#endif

static __device__ __forceinline__ float geluf(float v) {
    return 0.5f * v * (1.0f + erff(v * 0.70710678118654752f));
}
static __device__ __forceinline__ float eluf(float v) {
    return v > 0.0f ? v : expm1f(v);
}
static __device__ __forceinline__ unsigned pkbf(float a, float b) {
    union { __bf16 h[2]; unsigned u; } t;
    t.h[0] = (__bf16)a; t.h[1] = (__bf16)b;
    return t.u;
}
// (a', b') halves swap: a' = [b.hi->lo || a.hi], b' = [b.lo || a.lo->hi]
static __device__ __forceinline__ void swap32(unsigned a, unsigned b, unsigned& outA, unsigned& outB, int hi) {
#if __has_builtin(__builtin_amdgcn_permlane32_swap)
    u32x2 r = __builtin_amdgcn_permlane32_swap(a, b, false, false);
    outA = r[0]; outB = r[1];
#else
    unsigned ax = (unsigned)__shfl_xor((int)a, 32, 64);
    unsigned bx = (unsigned)__shfl_xor((int)b, 32, 64);
    outB = hi ? ax : b;
    outA = hi ? a : bx;
#endif
}

// async global -> LDS, 16 bytes per lane (dest must be lane-linear: base + 16*lane)
#if __has_builtin(__builtin_amdgcn_global_load_lds)
#define HAVE_GLOAD_LDS 1
static __device__ __forceinline__ void gl_lds16(const __bf16* g, __bf16* l) {
    __builtin_amdgcn_global_load_lds(
        (const __attribute__((address_space(1))) unsigned*)g,
        (__attribute__((address_space(3))) unsigned*)l, 16, 0, 0);
}
#else
#define HAVE_GLOAD_LDS 0
#endif

// ---------------- KNN: wave-per-query, ballot radix-select (r16 low-VGPR form) ----------------
// VGPR budget is the binding constraint here (r17 lesson: +52 VGPR -> occupancy 68%->29%, 94->121us).
// Scalar x loads + inline sqm recompute keep VGPR ~32 -> 8 waves/SIMD.
__global__ __launch_bounds__(256) void k_knn(const float* __restrict__ x,
                                             int* __restrict__ idx) {
    int q = blockIdx.x * 4 + (threadIdx.x >> 6);
    int lane = threadIdx.x & 63;
    int b = q >> 11, n = q & (Nn - 1);
    const float* xb = x + (size_t)b * Nn * 3;
    float xn0 = xb[n * 3], xn1 = xb[n * 3 + 1], xn2 = xb[n * 3 + 2];
    float sqn = xn0 * xn0 + xn1 * xn1 + xn2 * xn2;

    unsigned cand[32];
#pragma unroll
    for (int c = 0; c < 32; ++c) {
        int m = lane + 64 * c;
        float xm0 = xb[m * 3], xm1 = xb[m * 3 + 1], xm2 = xb[m * 3 + 2];
        float sqm = xm0 * xm0 + xm1 * xm1 + xm2 * xm2;
        float d = sqn + sqm - 2.0f * (xn0 * xm0 + xn1 * xm1 + xn2 * xm2);
        unsigned fb = __float_as_uint(d);
        cand[c] = (fb & 0x80000000u) ? ~fb : (fb | 0x80000000u);   // monotonic total order
    }

    unsigned prefix = 0u;
    for (int bit = 31; bit >= 0; --bit) {
        unsigned t = prefix | (1u << bit);
        // 4 independent counters: breaks the 32-deep serial add chain, zero VGPR cost
        int c0 = 0, c1 = 0, c2 = 0, c3 = 0;
#pragma unroll
        for (int c = 0; c < 32; c += 4) {
            c0 += (int)__popcll(__ballot(cand[c] < t));
            c1 += (int)__popcll(__ballot(cand[c + 1] < t));
            c2 += (int)__popcll(__ballot(cand[c + 2] < t));
            c3 += (int)__popcll(__ballot(cand[c + 3] < t));
        }
        int cnt = (c0 + c1) + (c2 + c3);
        if (cnt < KK) prefix = t;
    }

    unsigned long long lmask = (1ULL << lane) - 1ULL;
    int base = 0;
#pragma unroll
    for (int c = 0; c < 32; ++c) {
        bool sel = cand[c] < prefix;
        unsigned long long mk = __ballot(sel);
        int pos = base + (int)__popcll(mk & lmask);
        if (sel) idx[(size_t)q * KK + pos] = lane + 64 * c;
        base += (int)__popcll(mk);
    }
    for (int c = 0; c < 32 && base < KK; ++c) {
        bool eq = (cand[c] == prefix);
        unsigned long long mk = __ballot(eq);
        int pos = base + (int)__popcll(mk & lmask);
        if (eq && pos < KK) idx[(size_t)q * KK + pos] = lane + 64 * c;
        base += (int)__popcll(mk);
    }
}

// ---------------- feat @ W1 + b1 ----------------
__global__ __launch_bounds__(256) void k_h1(const float* __restrict__ x, const int* __restrict__ idx,
                                            const float* __restrict__ W1, const float* __restrict__ b1,
                                            float* __restrict__ h1) {
    int t = blockIdx.x * 256 + threadIdx.x;   // < B*N*K
    if (t >= Bb * Nn * KK) return;
    int bn = t / KK;
    int b = bn / Nn, n = bn % Nn;
    int j = idx[t];
    const float* xb = x + (size_t)b * Nn * 3;
    float xn0 = xb[n * 3], xn1 = xb[n * 3 + 1], xn2 = xb[n * 3 + 2];
    float f3 = xn0 - xb[j * 3], f4 = xn1 - xb[j * 3 + 1], f5 = xn2 - xb[j * 3 + 2];
    float* o = h1 + (size_t)t * 6;
#pragma unroll
    for (int c = 0; c < 6; ++c) {
        o[c] = b1[c] + xn0 * W1[0 * 6 + c] + xn1 * W1[1 * 6 + c] + xn2 * W1[2 * 6 + c]
             + f3 * W1[3 * 6 + c] + f4 * W1[4 * 6 + c] + f5 * W1[5 * 6 + c];
    }
}

// ---------------- two-stage BN stats, deterministic, coalesced ----------------
__global__ __launch_bounds__(256) void k_stats6_part(const float* __restrict__ v, int R, int nblk,
                                                     double* __restrict__ part) {
    int blk = blockIdx.x, tid = threadIdx.x;
    int rows = R / nblk;
    int r0 = blk * rows;
    double s[6] = {0, 0, 0, 0, 0, 0}, s2[6] = {0, 0, 0, 0, 0, 0};
    for (int r = r0 + tid; r < r0 + rows; r += 256) {
        const float* p = v + (size_t)r * 6;
#pragma unroll
        for (int c = 0; c < 6; ++c) { double t = p[c]; s[c] += t; s2[c] += t * t; }
    }
    __shared__ double sh[256][12];
#pragma unroll
    for (int c = 0; c < 6; ++c) { sh[tid][c] = s[c]; sh[tid][6 + c] = s2[c]; }
    __syncthreads();
    for (int st = 128; st > 0; st >>= 1) {
        if (tid < st) {
#pragma unroll
            for (int q = 0; q < 12; ++q) sh[tid][q] += sh[tid + st][q];
        }
        __syncthreads();
    }
    if (tid < 12) part[(size_t)blk * 12 + tid] = sh[0][tid];
}

// parallel finalizer: 192 threads = 12 stats x 16 groups
__global__ __launch_bounds__(256) void k_stats6_fin(const double* __restrict__ part, int nblk, int R,
                                                    float* __restrict__ mean, float* __restrict__ rstd) {
    __shared__ double sh[16][12];
    int t = threadIdx.x;
    if (t < 192) {
        int q = t % 12, g = t / 12;          // g < 16
        double s = 0.0;
        for (int b = g; b < nblk; b += 16) s += part[(size_t)b * 12 + q];
        sh[g][q] = s;
    }
    __syncthreads();
    if (t < 12) {
        double s = 0.0;
#pragma unroll
        for (int g = 0; g < 16; ++g) s += sh[g][t];
        sh[0][t] = s;
    }
    __syncthreads();
    if (t < 6) {
        double mu = sh[0][t] / R;
        double var = sh[0][6 + t] / R - mu * mu;
        mean[t] = (float)mu;
        rstd[t] = (float)(1.0 / sqrt(var + 1e-5));
    }
}

__global__ __launch_bounds__(256) void k_stats256_part(const float* __restrict__ v, int R, int nblk,
                                                       double* __restrict__ part) {
    int blk = blockIdx.x, c = threadIdx.x;
    int rows = R / nblk;
    int r0 = blk * rows;
    double s = 0.0, s2 = 0.0;
    for (int r = r0; r < r0 + rows; ++r) {
        double t = v[(size_t)r * Ee + c];
        s += t; s2 += t * t;
    }
    part[(size_t)blk * (2 * Ee) + c] = s;
    part[(size_t)blk * (2 * Ee) + Ee + c] = s2;
}

// 4 independent accumulators break the serial dependent-load chain
__global__ __launch_bounds__(256) void k_stats256_fin(const double* __restrict__ part, int nblk, int R,
                                                      float* __restrict__ mean, float* __restrict__ rstd) {
    int c = threadIdx.x;
    double s0 = 0.0, s1 = 0.0, s2a = 0.0, s3 = 0.0;
    double t0 = 0.0, t1 = 0.0, t2 = 0.0, t3 = 0.0;
    for (int b = 0; b < nblk; b += 4) {
        s0 += part[(size_t)b * (2 * Ee) + c];
        s1 += part[(size_t)(b + 1) * (2 * Ee) + c];
        s2a += part[(size_t)(b + 2) * (2 * Ee) + c];
        s3 += part[(size_t)(b + 3) * (2 * Ee) + c];
        t0 += part[(size_t)b * (2 * Ee) + Ee + c];
        t1 += part[(size_t)(b + 1) * (2 * Ee) + Ee + c];
        t2 += part[(size_t)(b + 2) * (2 * Ee) + Ee + c];
        t3 += part[(size_t)(b + 3) * (2 * Ee) + Ee + c];
    }
    double s = (s0 + s1) + (s2a + s3);
    double s2 = (t0 + t1) + (t2 + t3);
    double mu = s / R;
    double var = s2 / R - mu * mu;
    mean[c] = (float)mu;
    rstd[c] = (float)(1.0 / sqrt(var + 1e-5));
}

// ---------------- BN1+ELU, max over K, @W2+b2 ----------------
__global__ __launch_bounds__(256) void k_maxh2(const float* __restrict__ h1,
                                               const float* __restrict__ mean1, const float* __restrict__ rstd1,
                                               const float* __restrict__ g1, const float* __restrict__ be1,
                                               const float* __restrict__ W2, const float* __restrict__ b2,
                                               float* __restrict__ x0) {
    int bn = blockIdx.x;
    int t = threadIdx.x;
    __shared__ float hval[KK][6];
    __shared__ float hmax[6];
    if (t < KK * 6) {
        int k = t / 6, c = t % 6;
        float v = h1[((size_t)bn * KK + k) * 6 + c];
        v = (v - mean1[c]) * rstd1[c] * g1[c] + be1[c];
        hval[k][c] = eluf(v);
    }
    __syncthreads();
    if (t < 6) {
        float m = -FLT_MAX;
        for (int k = 0; k < KK; ++k) m = fmaxf(m, hval[k][t]);
        hmax[t] = m;
    }
    __syncthreads();
    float s = b2[t];
#pragma unroll
    for (int i = 0; i < 6; ++i) s += hmax[i] * W2[i * Ee + t];
    x0[(size_t)bn * Ee + t] = s;
}

// ---------------- fused BN2-apply + layer-0 LN (wave per row) ----------------
__global__ __launch_bounds__(256) void k_bnln(float* __restrict__ X,
                                              const float* __restrict__ mean2, const float* __restrict__ rstd2,
                                              const float* __restrict__ g2, const float* __restrict__ be2,
                                              const float* __restrict__ g, const float* __restrict__ b,
                                              __bf16* __restrict__ Yb) {
    int row = blockIdx.x * 4 + (threadIdx.x >> 6);
    int lane = threadIdx.x & 63;
    int c0 = lane * 4;
    float4 v = *(const float4*)(X + (size_t)row * Ee + c0);
    v.x = eluf((v.x - mean2[c0 + 0]) * rstd2[c0 + 0] * g2[c0 + 0] + be2[c0 + 0]);
    v.y = eluf((v.y - mean2[c0 + 1]) * rstd2[c0 + 1] * g2[c0 + 1] + be2[c0 + 1]);
    v.z = eluf((v.z - mean2[c0 + 2]) * rstd2[c0 + 2] * g2[c0 + 2] + be2[c0 + 2]);
    v.w = eluf((v.w - mean2[c0 + 3]) * rstd2[c0 + 3] * g2[c0 + 3] + be2[c0 + 3]);
    *(float4*)(X + (size_t)row * Ee + c0) = v;
    float s = v.x + v.y + v.z + v.w;
#pragma unroll
    for (int off = 32; off; off >>= 1) s += __shfl_xor(s, off, 64);
    float mu = s * (1.0f / Ee);
    float d0 = v.x - mu, d1 = v.y - mu, d2 = v.z - mu, d3 = v.w - mu;
    float s2 = d0 * d0 + d1 * d1 + d2 * d2 + d3 * d3;
#pragma unroll
    for (int off = 32; off; off >>= 1) s2 += __shfl_xor(s2, off, 64);
    float rstd = 1.0f / sqrtf(s2 * (1.0f / Ee) + 1e-5f);
    float4 gv = *(const float4*)(g + c0);
    float4 bv = *(const float4*)(b + c0);
    bf16x4 o;
    o[0] = (__bf16)(gv.x * d0 * rstd + bv.x);
    o[1] = (__bf16)(gv.y * d1 * rstd + bv.y);
    o[2] = (__bf16)(gv.z * d2 * rstd + bv.z);
    o[3] = (__bf16)(gv.w * d3 * rstd + bv.w);
    *(bf16x4*)(Yb + (size_t)row * Ee + c0) = o;
}

// ---------------- LayerNorm -> bf16 (one wave per row of 256) ----------------
__global__ __launch_bounds__(256) void k_lnb(const float* __restrict__ X,
                                             const float* __restrict__ g, const float* __restrict__ b,
                                             __bf16* __restrict__ Yb) {
    int row = blockIdx.x * 4 + (threadIdx.x >> 6);
    int lane = threadIdx.x & 63;
    float4 v = *(const float4*)(X + (size_t)row * Ee + lane * 4);
    float s = v.x + v.y + v.z + v.w;
#pragma unroll
    for (int off = 32; off; off >>= 1) s += __shfl_xor(s, off, 64);
    float mu = s * (1.0f / Ee);
    float d0 = v.x - mu, d1 = v.y - mu, d2 = v.z - mu, d3 = v.w - mu;
    float s2 = d0 * d0 + d1 * d1 + d2 * d2 + d3 * d3;
#pragma unroll
    for (int off = 32; off; off >>= 1) s2 += __shfl_xor(s2, off, 64);
    float rstd = 1.0f / sqrtf(s2 * (1.0f / Ee) + 1e-5f);
    float4 gv = *(const float4*)(g + lane * 4);
    float4 bv = *(const float4*)(b + lane * 4);
    bf16x4 o;
    o[0] = (__bf16)(gv.x * d0 * rstd + bv.x);
    o[1] = (__bf16)(gv.y * d1 * rstd + bv.y);
    o[2] = (__bf16)(gv.z * d2 * rstd + bv.z);
    o[3] = (__bf16)(gv.w * d3 * rstd + bv.w);
    *(bf16x4*)(Yb + (size_t)row * Ee + lane * 4) = o;
}

// ---------------- fused weight transpose + bf16 convert for all 4 weight sets ----------------
__global__ __launch_bounds__(256) void k_wtall(const float* __restrict__ attn_w, const float* __restrict__ out_w,
                                               const float* __restrict__ ff1_w, const float* __restrict__ ff2_w,
                                               __bf16* __restrict__ attn_wt, __bf16* __restrict__ out_wt,
                                               __bf16* __restrict__ ff1_wt, __bf16* __restrict__ ff2_wt) {
    int bid = blockIdx.x;
    const float* w; __bf16* wt; int K, N, n0, k0;
    if (bid < 144) {           // attn: 12 x 4 x 3
        int r = bid; int z = r / 48; r %= 48;
        K = Ee; N = QKV; n0 = (r % 12) * 64; k0 = (r / 12) * 64;
        w = attn_w + (size_t)z * K * N; wt = attn_wt + (size_t)z * K * N;
    } else if (bid < 192) {    // out: 4 x 4 x 3
        int r = bid - 144; int z = r / 16; r %= 16;
        K = Ee; N = Ee; n0 = (r % 4) * 64; k0 = (r / 4) * 64;
        w = out_w + (size_t)z * K * N; wt = out_wt + (size_t)z * K * N;
    } else if (bid < 288) {    // ff1: 8 x 4 x 3
        int r = bid - 192; int z = r / 32; r %= 32;
        K = Ee; N = FF; n0 = (r % 8) * 64; k0 = (r / 8) * 64;
        w = ff1_w + (size_t)z * K * N; wt = ff1_wt + (size_t)z * K * N;
    } else {                   // ff2: 4 x 8 x 3
        int r = bid - 288; int z = r / 32; r %= 32;
        K = FF; N = Ee; n0 = (r % 4) * 64; k0 = (r / 4) * 64;
        w = ff2_w + (size_t)z * K * N; wt = ff2_wt + (size_t)z * K * N;
    }
    __shared__ float L[64][65];
    int t = threadIdx.x;
    int r = t >> 4, c4 = (t & 15) * 4;
#pragma unroll
    for (int j = 0; j < 4; ++j) {
        float4 v = *(const float4*)(w + (size_t)(k0 + r + j * 16) * N + n0 + c4);
        L[r + j * 16][c4 + 0] = v.x; L[r + j * 16][c4 + 1] = v.y;
        L[r + j * 16][c4 + 2] = v.z; L[r + j * 16][c4 + 3] = v.w;
    }
    __syncthreads();
#pragma unroll
    for (int j = 0; j < 4; ++j) {
        int nn = r + j * 16;
        bf16x4 o;
        o[0] = (__bf16)L[c4 + 0][nn]; o[1] = (__bf16)L[c4 + 1][nn];
        o[2] = (__bf16)L[c4 + 2][nn]; o[3] = (__bf16)L[c4 + 3][nn];
        *(bf16x4*)(wt + (size_t)(n0 + nn) * K + k0 + c4) = o;
    }
}

// ---------------- bf16 MFMA GEMM, 64x128 tile ----------------
// OUTM: 0=f32 1=bf16 ; RESM: 0=none 1=bf16 2=f32 ; ACT: 0=none 1=gelu
// QKVM=1: q-cols (<Ee) scaled by CEXP -> qkvb; K-cols -> kp[b][h][key][d] (per-head packed);
//         V-cols -> vt[b][h][key/32][d][key%32]; K/V NOT written to qkvb (attn reads Kp/Vt).
template<int OUTM, int RESM, int ACT, int QKVM>
__global__ __launch_bounds__(256) void k_mgemm(const __bf16* __restrict__ Ain,
                                               const __bf16* __restrict__ Wt,
                                               const float* __restrict__ bias,
                                               const void* __restrict__ res,
                                               void* __restrict__ out,
                                               int Kd, int Nd,
                                               __bf16* __restrict__ kp,
                                               __bf16* __restrict__ vt) {
    __shared__ __bf16 As[64 * 32];
    __shared__ __bf16 Bs[128 * 32];
    int tid = threadIdx.x;
    int n0 = blockIdx.x * 128, m0 = blockIdx.y * 64;
    int wave = tid >> 6, lane = tid & 63;
    int wr = wave >> 1, wc = wave & 1;      // wave rows: wr*32, cols: wc*64
    int t = lane & 15, gg = lane >> 4;
    f32x4 acc[2][4];
#pragma unroll
    for (int m = 0; m < 2; ++m)
#pragma unroll
        for (int nn = 0; nn < 4; ++nn) acc[m][nn] = (f32x4){0.f, 0.f, 0.f, 0.f};
    int r0 = tid >> 2, g0 = tid & 3;        // rows 0..63, 8-col groups
    for (int kt = 0; kt < Kd; kt += 32) {
#if HAVE_GLOAD_LDS
        __syncthreads();          // prior iteration's frag reads complete before overwrite
        gl_lds16(Ain + (size_t)(m0 + r0) * Kd + kt + g0 * 8, &As[r0 * 32 + g0 * 8]);
        gl_lds16(Wt + (size_t)(n0 + r0) * Kd + kt + g0 * 8, &Bs[r0 * 32 + g0 * 8]);
        gl_lds16(Wt + (size_t)(n0 + 64 + r0) * Kd + kt + g0 * 8, &Bs[(64 + r0) * 32 + g0 * 8]);
        __syncthreads();          // drains vmcnt: LDS tiles ready
#else
        bf16x8 a0 = *(const bf16x8*)(Ain + (size_t)(m0 + r0) * Kd + kt + g0 * 8);
        bf16x8 w0 = *(const bf16x8*)(Wt + (size_t)(n0 + r0) * Kd + kt + g0 * 8);
        bf16x8 w1 = *(const bf16x8*)(Wt + (size_t)(n0 + 64 + r0) * Kd + kt + g0 * 8);
        __syncthreads();
        *(bf16x8*)&As[r0 * 32 + g0 * 8] = a0;
        *(bf16x8*)&Bs[r0 * 32 + g0 * 8] = w0;
        *(bf16x8*)&Bs[(64 + r0) * 32 + g0 * 8] = w1;
        __syncthreads();
#endif
        bf16x8 af[2], bfr[4];
#pragma unroll
        for (int m = 0; m < 2; ++m) af[m] = *(const bf16x8*)&As[(wr * 32 + m * 16 + t) * 32 + gg * 8];
#pragma unroll
        for (int nn = 0; nn < 4; ++nn) bfr[nn] = *(const bf16x8*)&Bs[(wc * 64 + nn * 16 + t) * 32 + gg * 8];
#pragma unroll
        for (int m = 0; m < 2; ++m)
#pragma unroll
            for (int nn = 0; nn < 4; ++nn)
                acc[m][nn] = __builtin_amdgcn_mfma_f32_16x16x32_bf16(af[m], bfr[nn], acc[m][nn], 0, 0, 0);
    }
#pragma unroll
    for (int m = 0; m < 2; ++m) {
#pragma unroll
        for (int nn = 0; nn < 4; ++nn) {
            int ocol = n0 + wc * 64 + nn * 16 + t;
            float bv = bias[ocol];
            float vv[4];
#pragma unroll
            for (int j = 0; j < 4; ++j) {
                int orow = m0 + wr * 32 + m * 16 + gg * 4 + j;
                float v = acc[m][nn][j] + bv;
                if (RESM == 1) v += (float)((const __bf16*)res)[(size_t)orow * Nd + ocol];
                if (RESM == 2) v += ((const float*)res)[(size_t)orow * Nd + ocol];
                if (ACT == 1) v = geluf(v);
                if (QKVM == 1 && ocol < Ee) v *= CEXP;   // pre-scale q for attn exp2
                vv[j] = v;
                if (!(QKVM == 1 && ocol >= Ee)) {        // K/V skip qkvb; go to Kp/Vt instead
                    if (OUTM == 0) ((float*)out)[(size_t)orow * Nd + ocol] = v;
                    else           ((__bf16*)out)[(size_t)orow * Nd + ocol] = (__bf16)v;
                }
            }
            if (QKVM == 1 && ocol >= Ee && ocol < 2 * Ee) {   // per-head packed K store
                int d = ocol - Ee;
                int h = d >> 5, dd = d & 31;
                int orow0 = m0 + wr * 32 + m * 16 + gg * 4;
                int bi = orow0 >> 11, n = orow0 & (Nn - 1);
                __bf16* kb = kp + (((size_t)(bi * Hh + h) * Nn + n) * DH + dd);
                kb[0] = (__bf16)vv[0]; kb[DH] = (__bf16)vv[1];
                kb[2 * DH] = (__bf16)vv[2]; kb[3 * DH] = (__bf16)vv[3];
            }
            if (QKVM == 1 && ocol >= 2 * Ee) {           // blocked-transpose V store
                int d = ocol - 2 * Ee;
                int h = d >> 5, dd = d & 31;
                int orow0 = m0 + wr * 32 + m * 16 + gg * 4;
                int bi = orow0 >> 11, n = orow0 & (Nn - 1);
                int kc = n >> 5, k5 = n & 31;
                bf16x4 o;
                o[0] = (__bf16)vv[0]; o[1] = (__bf16)vv[1];
                o[2] = (__bf16)vv[2]; o[3] = (__bf16)vv[3];
                *(bf16x4*)(vt + ((((size_t)(bi * Hh + h) * (Nn / 32) + kc) * DH + dd) << 5) + k5) = o;
            }
        }
    }
}

// ---------------- swapped-operand 32x32 MFMA flash attention: no LDS, no barriers ----------------
// Q (pre-scaled) from qkvb; K from per-head packed Kp; V from 32-key-blocked Vt.
__global__ __launch_bounds__(256) void k_attn(const __bf16* __restrict__ qkv,
                                              const __bf16* __restrict__ kp,
                                              const __bf16* __restrict__ vt,
                                              __bf16* __restrict__ obf) {
    int wgid = (blockIdx.x & 7) * 128 + (blockIdx.x >> 3);   // 1024 blocks, bijective
    int qg = wgid & 15;
    int bh = wgid >> 4;
    int h = bh & 7, b = bh >> 3;
    int wave = threadIdx.x >> 6, lane = threadIdx.x & 63;
    int l31 = lane & 31, hi = lane >> 5;
    int qb = qg * 128 + wave * 32;
    const size_t base = (size_t)b * Nn * QKV;

    const __bf16* qrow = qkv + base + (size_t)(qb + l31) * QKV + h * DH;
    bf16x8 qf0 = *(const bf16x8*)(qrow + hi * 8);
    bf16x8 qf1 = *(const bf16x8*)(qrow + 16 + hi * 8);

    const __bf16* kpb = kp + ((size_t)(b * Hh + h) * Nn + l31) * DH + hi * 8;   // + c0*DH per chunk
    const __bf16* vtb = vt + ((size_t)(b * Hh + h) * (Nn / 32)) * DH * 32 + l31 * 32 + hi * 8;

    f32x16 oacc = {0.f,0.f,0.f,0.f,0.f,0.f,0.f,0.f,0.f,0.f,0.f,0.f,0.f,0.f,0.f,0.f};
    float lsum = 0.0f;

    for (int c0 = 0; c0 < Nn; c0 += 32) {
        const __bf16* kr = kpb + (size_t)c0 * DH;
        bf16x8 kf0 = *(const bf16x8*)kr;           // K[c0+l31][d=hi*8..]
        bf16x8 kf1 = *(const bf16x8*)(kr + 16);    // K[c0+l31][d=16+hi*8..]

        f32x16 s = {0.f,0.f,0.f,0.f,0.f,0.f,0.f,0.f,0.f,0.f,0.f,0.f,0.f,0.f,0.f,0.f};
        s = __builtin_amdgcn_mfma_f32_32x32x16_bf16(kf0, qf0, s, 0, 0, 0);
        s = __builtin_amdgcn_mfma_f32_32x32x16_bf16(kf1, qf1, s, 0, 0, 0);
        // lane holds S^T[key=(reg&3)+8*(reg>>2)+4*hi][q=l31], already in log2 units

        float p[16];
#pragma unroll
        for (int i = 0; i < 16; ++i) p[i] = EXP2(s[i]);
        float s0 = (p[0] + p[1]) + (p[2] + p[3]);
        float s1 = (p[4] + p[5]) + (p[6] + p[7]);
        float s2r = (p[8] + p[9]) + (p[10] + p[11]);
        float s3 = (p[12] + p[13]) + (p[14] + p[15]);
        lsum += (s0 + s1) + (s2r + s3);

        unsigned d0 = pkbf(p[0], p[1]),  d1 = pkbf(p[2], p[3]);
        unsigned d2 = pkbf(p[4], p[5]),  d3 = pkbf(p[6], p[7]);
        unsigned d4 = pkbf(p[8], p[9]),  d5 = pkbf(p[10], p[11]);
        unsigned d6 = pkbf(p[12], p[13]), d7 = pkbf(p[14], p[15]);
        unsigned w0a, w0b, w1a, w1b, w2a, w2b, w3a, w3b;
        swap32(d2, d0, w2a, w0a, hi);
        swap32(d3, d1, w3a, w1a, hi);
        swap32(d6, d4, w2b, w0b, hi);
        swap32(d7, d5, w3b, w1b, hi);
        union { unsigned u[4]; bf16x8 v; } pa0, pa1;
        pa0.u[0] = w0a; pa0.u[1] = w1a; pa0.u[2] = w2a; pa0.u[3] = w3a;
        pa1.u[0] = w0b; pa1.u[1] = w1b; pa1.u[2] = w2b; pa1.u[3] = w3b;

        const __bf16* vp = vtb + (size_t)(c0 >> 5) * (DH * 32);
        bf16x8 vf0 = *(const bf16x8*)vp;           // V[key=hi*8+j][d=l31]
        bf16x8 vf1 = *(const bf16x8*)(vp + 16);    // V[key=16+hi*8+j][d=l31]

        oacc = __builtin_amdgcn_mfma_f32_32x32x16_bf16(pa0.v, vf0, oacc, 0, 0, 0);
        oacc = __builtin_amdgcn_mfma_f32_32x32x16_bf16(pa1.v, vf1, oacc, 0, 0, 0);
    }

    float ltot = lsum + __shfl_xor(lsum, 32, 64);
    float invl = 1.0f / ltot;     // valid for q = l31
#pragma unroll
    for (int reg = 0; reg < 16; ++reg) {
        int row = (reg & 3) + 8 * (reg >> 2) + 4 * hi;
        float iv = __shfl(invl, row, 64);
        obf[((size_t)(b * Nn + qb + row)) * Ee + h * DH + l31] = (__bf16)(oacc[reg] * iv);
    }
}

// ---------------- decoder ----------------
__global__ __launch_bounds__(256) void k_meanpart(const float* __restrict__ X, float* __restrict__ pm) {
    int chunk = blockIdx.x, b = blockIdx.y;
    int e = threadIdx.x;
    float s = 0.0f;
    for (int n = chunk * 256; n < chunk * 256 + 256; ++n)
        s += X[((size_t)b * Nn + n) * Ee + e];
    pm[(size_t)(b * 8 + chunk) * Ee + e] = s;
}
__global__ __launch_bounds__(256) void k_meanfin(const float* __restrict__ pm, float* __restrict__ m) {
    int i = blockIdx.x * 256 + threadIdx.x;
    int b = i >> 8, e = i & 255;
    float s = 0.0f;
    for (int c = 0; c < 8; ++c) s += pm[(size_t)(b * 8 + c) * Ee + e];
    m[i] = s * (1.0f / Nn);
}
__global__ __launch_bounds__(512) void k_dec1(const float* __restrict__ m, const float* __restrict__ w,
                                              const float* __restrict__ bias, float* __restrict__ t1) {
    int b = blockIdx.x, j = threadIdx.x;
    float s = bias[j];
    for (int i = 0; i < Ee; ++i) s += m[b * Ee + i] * w[i * FF + j];
    t1[b * FF + j] = geluf(s);
}
__global__ __launch_bounds__(256) void k_dec2(const float* __restrict__ t1, const float* __restrict__ w,
                                              const float* __restrict__ bias, float* __restrict__ out) {
    int i = blockIdx.x * 256 + threadIdx.x;
    int b = i / 3072, j = i % 3072;
    float s = bias[j];
    for (int k = 0; k < FF; ++k) s += t1[b * FF + k] * w[k * 3072 + j];
    out[i] = s;
}

extern "C" void kernel_launch(void* const* d_in, const int* in_sizes, int n_in,
                              void* d_out, int out_size, void* d_ws, size_t ws_size,
                              hipStream_t stream) {
    const float* x      = (const float*)d_in[0];
    const float* W1     = (const float*)d_in[1];
    const float* b1     = (const float*)d_in[2];
    const float* g1     = (const float*)d_in[3];
    const float* be1    = (const float*)d_in[4];
    const float* W2     = (const float*)d_in[5];
    const float* b2     = (const float*)d_in[6];
    const float* g2     = (const float*)d_in[7];
    const float* be2    = (const float*)d_in[8];
    const float* ln1_g  = (const float*)d_in[9];
    const float* ln1_b  = (const float*)d_in[10];
    const float* attn_w = (const float*)d_in[11];
    const float* attn_b = (const float*)d_in[12];
    const float* out_w  = (const float*)d_in[13];
    const float* out_b  = (const float*)d_in[14];
    const float* ln2_g  = (const float*)d_in[15];
    const float* ln2_b  = (const float*)d_in[16];
    const float* ff1_w  = (const float*)d_in[17];
    const float* ff1_b  = (const float*)d_in[18];
    const float* ff2_w  = (const float*)d_in[19];
    const float* ff2_b  = (const float*)d_in[20];
    const float* dec1_w = (const float*)d_in[21];
    const float* dec1_b = (const float*)d_in[22];
    const float* dec2_w = (const float*)d_in[23];
    const float* dec2_b = (const float*)d_in[24];
    (void)in_sizes; (void)n_in; (void)out_size; (void)ws_size;

    const size_t MN = (size_t)Bb * Nn * Ee;            // 16384*256

    float*  A    = (float*)d_ws;                       // xcur fp32
    __bf16* Ab   = (__bf16*)(A + MN);                  // hn bf16
    __bf16* qkvb = Ab + MN;                            // qkv bf16 (only q-cols written in steady state)
    __bf16* obf  = qkvb + (size_t)Bb * Nn * QKV;       // attn out bf16
    __bf16* ffb  = obf + MN;                           // ff intermediate bf16 (aliases Kp+Vt)
    __bf16* attn_wt = ffb + (size_t)Bb * Nn * FF;      // transposed bf16 weights
    __bf16* out_wt  = attn_wt + (size_t)NB * QKV * Ee;
    __bf16* ff1_wt  = out_wt + (size_t)NB * Ee * Ee;
    __bf16* ff2_wt  = ff1_wt + (size_t)NB * FF * Ee;
    float*  S       = (float*)(ff2_wt + (size_t)NB * Ee * FF);

    // Kp[b][h][key][d] and Vt32[b][h][key/32][d][key%32] alias ffb
    __bf16* Vt = ffb;
    __bf16* Kp = ffb + (size_t)Bb * Hh * Nn * DH;

    float* mean1 = S,      *rstd1 = S + 16;
    float* mean2 = S + 32, *rstd2 = S + 32 + Ee;
    float* pm    = S + 1024;
    float* mvec  = pm + 64 * Ee;
    float* t1    = mvec + Bb * Ee;
    double* part6   = (double*)(S + 32768);
    double* part256 = part6 + 512 * 12;

    // ARPE scratch aliases qkvb (dead until first qkv GEMM)
    int*   idx = (int*)qkvb;
    float* h1  = (float*)(idx + (size_t)Bb * Nn * KK);

    // fused weight convert+transpose (independent of ARPE)
    k_wtall<<<384, 256, 0, stream>>>(attn_w, out_w, ff1_w, ff2_w,
                                     attn_wt, out_wt, ff1_wt, ff2_wt);

    k_knn <<<Bb * Nn / 4, 256, 0, stream>>>(x, idx);
    k_h1  <<<(Bb * Nn * KK) / 256, 256, 0, stream>>>(x, idx, W1, b1, h1);
    k_stats6_part<<<512, 256, 0, stream>>>(h1, Bb * Nn * KK, 512, part6);
    k_stats6_fin<<<1, 256, 0, stream>>>(part6, 512, Bb * Nn * KK, mean1, rstd1);
    k_maxh2<<<Bb * Nn, 256, 0, stream>>>(h1, mean1, rstd1, g1, be1, W2, b2, A);
    k_stats256_part<<<64, 256, 0, stream>>>(A, Bb * Nn, 64, part256);
    k_stats256_fin<<<1, 256, 0, stream>>>(part256, 64, Bb * Nn, mean2, rstd2);
    // fused BN2-apply + layer-0 LN
    k_bnln<<<Bb * Nn / 4, 256, 0, stream>>>(A, mean2, rstd2, g2, be2, ln1_g, ln1_b, Ab);

    const int M = Bb * Nn;
    for (int i = 0; i < NB; ++i) {
        if (i > 0)
            k_lnb<<<M / 4, 256, 0, stream>>>(A, ln1_g + i * Ee, ln1_b + i * Ee, Ab);
        k_mgemm<1, 0, 0, 1><<<dim3(QKV / 128, M / 64), 256, 0, stream>>>(
            Ab, attn_wt + (size_t)i * QKV * Ee, attn_b + i * QKV, nullptr, qkvb, Ee, QKV, Kp, Vt);
        k_attn<<<Bb * Hh * 16, 256, 0, stream>>>(qkvb, Kp, Vt, obf);
        k_mgemm<0, 1, 0, 0><<<dim3(Ee / 128, M / 64), 256, 0, stream>>>(
            obf, out_wt + (size_t)i * Ee * Ee, out_b + i * Ee, Ab, A, Ee, Ee, nullptr, nullptr);
        k_lnb<<<M / 4, 256, 0, stream>>>(A, ln2_g + i * Ee, ln2_b + i * Ee, Ab);
        k_mgemm<1, 0, 1, 0><<<dim3(FF / 128, M / 64), 256, 0, stream>>>(
            Ab, ff1_wt + (size_t)i * FF * Ee, ff1_b + i * FF, nullptr, ffb, Ee, FF, nullptr, nullptr);
        k_mgemm<0, 2, 0, 0><<<dim3(Ee / 128, M / 64), 256, 0, stream>>>(
            ffb, ff2_wt + (size_t)i * Ee * FF, ff2_b + i * Ee, A, A, FF, Ee, nullptr, nullptr);
    }

    k_meanpart<<<dim3(8, Bb), 256, 0, stream>>>(A, pm);
    k_meanfin<<<Bb, 256, 0, stream>>>(pm, mvec);
    k_dec1<<<Bb, FF, 0, stream>>>(mvec, dec1_w, dec1_b, t1);
    k_dec2<<<(Bb * OUTPTS * 3) / 256, 256, 0, stream>>>(t1, dec2_w, dec2_b, (float*)d_out);
}

// Round 19
// 711.700 us; speedup vs baseline: 1.0670x; 1.0274x over previous
//
#include <hip/hip_runtime.h>
#include <math.h>
#include <float.h>

#define Bb 8
#define Nn 2048
#define Ee 256
#define Hh 8
#define NB 3
#define KK 32
#define DH 32
#define QKV 768
#define FF 512
#define OUTPTS 1024

#define CEXP 0.25509667991878083f   // (1/sqrt(32)) * log2(e)

typedef __bf16 bf16x8 __attribute__((ext_vector_type(8)));
typedef __bf16 bf16x4 __attribute__((ext_vector_type(4)));
typedef float f32x4 __attribute__((ext_vector_type(4)));
typedef float f32x16 __attribute__((ext_vector_type(16)));
typedef unsigned u32x2 __attribute__((ext_vector_type(2)));

#if __has_builtin(__builtin_amdgcn_exp2f)
#define EXP2(x) __builtin_amdgcn_exp2f(x)
#else
#define EXP2(x) exp2f(x)
#endif

static __device__ __forceinline__ float geluf(float v) {
    return 0.5f * v * (1.0f + erff(v * 0.70710678118654752f));
}
static __device__ __forceinline__ float eluf(float v) {
    return v > 0.0f ? v : expm1f(v);
}
static __device__ __forceinline__ unsigned pkbf(float a, float b) {
    union { __bf16 h[2]; unsigned u; } t;
    t.h[0] = (__bf16)a; t.h[1] = (__bf16)b;
    return t.u;
}
// (a', b') halves swap: a' = [b.hi->lo || a.hi], b' = [b.lo || a.lo->hi]
static __device__ __forceinline__ void swap32(unsigned a, unsigned b, unsigned& outA, unsigned& outB, int hi) {
#if __has_builtin(__builtin_amdgcn_permlane32_swap)
    u32x2 r = __builtin_amdgcn_permlane32_swap(a, b, false, false);
    outA = r[0]; outB = r[1];
#else
    unsigned ax = (unsigned)__shfl_xor((int)a, 32, 64);
    unsigned bx = (unsigned)__shfl_xor((int)b, 32, 64);
    outB = hi ? ax : b;
    outA = hi ? a : bx;
#endif
}

// async global -> LDS, 16 bytes per lane (dest must be lane-linear: base + 16*lane)
#if __has_builtin(__builtin_amdgcn_global_load_lds)
#define HAVE_GLOAD_LDS 1
static __device__ __forceinline__ void gl_lds16(const __bf16* g, __bf16* l) {
    __builtin_amdgcn_global_load_lds(
        (const __attribute__((address_space(1))) unsigned*)g,
        (__attribute__((address_space(3))) unsigned*)l, 16, 0, 0);
}
#else
#define HAVE_GLOAD_LDS 0
#endif

// ---------------- KNN: wave-per-query, ballot radix-select (r16 low-VGPR form) ----------------
// VGPR budget is the binding constraint here (r17 lesson: +52 VGPR -> occupancy 68%->29%, 94->121us).
__global__ __launch_bounds__(256) void k_knn(const float* __restrict__ x,
                                             int* __restrict__ idx) {
    int q = blockIdx.x * 4 + (threadIdx.x >> 6);
    int lane = threadIdx.x & 63;
    int b = q >> 11, n = q & (Nn - 1);
    const float* xb = x + (size_t)b * Nn * 3;
    float xn0 = xb[n * 3], xn1 = xb[n * 3 + 1], xn2 = xb[n * 3 + 2];
    float sqn = xn0 * xn0 + xn1 * xn1 + xn2 * xn2;

    unsigned cand[32];
#pragma unroll
    for (int c = 0; c < 32; ++c) {
        int m = lane + 64 * c;
        float xm0 = xb[m * 3], xm1 = xb[m * 3 + 1], xm2 = xb[m * 3 + 2];
        float sqm = xm0 * xm0 + xm1 * xm1 + xm2 * xm2;
        float d = sqn + sqm - 2.0f * (xn0 * xm0 + xn1 * xm1 + xn2 * xm2);
        unsigned fb = __float_as_uint(d);
        cand[c] = (fb & 0x80000000u) ? ~fb : (fb | 0x80000000u);   // monotonic total order
    }

    unsigned prefix = 0u;
    for (int bit = 31; bit >= 0; --bit) {
        unsigned t = prefix | (1u << bit);
        int c0 = 0, c1 = 0, c2 = 0, c3 = 0;
#pragma unroll
        for (int c = 0; c < 32; c += 4) {
            c0 += (int)__popcll(__ballot(cand[c] < t));
            c1 += (int)__popcll(__ballot(cand[c + 1] < t));
            c2 += (int)__popcll(__ballot(cand[c + 2] < t));
            c3 += (int)__popcll(__ballot(cand[c + 3] < t));
        }
        int cnt = (c0 + c1) + (c2 + c3);
        if (cnt < KK) prefix = t;
    }

    unsigned long long lmask = (1ULL << lane) - 1ULL;
    int base = 0;
#pragma unroll
    for (int c = 0; c < 32; ++c) {
        bool sel = cand[c] < prefix;
        unsigned long long mk = __ballot(sel);
        int pos = base + (int)__popcll(mk & lmask);
        if (sel) idx[(size_t)q * KK + pos] = lane + 64 * c;
        base += (int)__popcll(mk);
    }
    for (int c = 0; c < 32 && base < KK; ++c) {
        bool eq = (cand[c] == prefix);
        unsigned long long mk = __ballot(eq);
        int pos = base + (int)__popcll(mk & lmask);
        if (eq && pos < KK) idx[(size_t)q * KK + pos] = lane + 64 * c;
        base += (int)__popcll(mk);
    }
}

// ---------------- feat @ W1 + b1 ----------------
__global__ __launch_bounds__(256) void k_h1(const float* __restrict__ x, const int* __restrict__ idx,
                                            const float* __restrict__ W1, const float* __restrict__ b1,
                                            float* __restrict__ h1) {
    int t = blockIdx.x * 256 + threadIdx.x;   // < B*N*K
    if (t >= Bb * Nn * KK) return;
    int bn = t / KK;
    int b = bn / Nn, n = bn % Nn;
    int j = idx[t];
    const float* xb = x + (size_t)b * Nn * 3;
    float xn0 = xb[n * 3], xn1 = xb[n * 3 + 1], xn2 = xb[n * 3 + 2];
    float f3 = xn0 - xb[j * 3], f4 = xn1 - xb[j * 3 + 1], f5 = xn2 - xb[j * 3 + 2];
    float* o = h1 + (size_t)t * 6;
#pragma unroll
    for (int c = 0; c < 6; ++c) {
        o[c] = b1[c] + xn0 * W1[0 * 6 + c] + xn1 * W1[1 * 6 + c] + xn2 * W1[2 * 6 + c]
             + f3 * W1[3 * 6 + c] + f4 * W1[4 * 6 + c] + f5 * W1[5 * 6 + c];
    }
}

// ---------------- two-stage BN stats, deterministic, coalesced ----------------
__global__ __launch_bounds__(256) void k_stats6_part(const float* __restrict__ v, int R, int nblk,
                                                     double* __restrict__ part) {
    int blk = blockIdx.x, tid = threadIdx.x;
    int rows = R / nblk;
    int r0 = blk * rows;
    double s[6] = {0, 0, 0, 0, 0, 0}, s2[6] = {0, 0, 0, 0, 0, 0};
    for (int r = r0 + tid; r < r0 + rows; r += 256) {
        const float* p = v + (size_t)r * 6;
#pragma unroll
        for (int c = 0; c < 6; ++c) { double t = p[c]; s[c] += t; s2[c] += t * t; }
    }
    __shared__ double sh[256][12];
#pragma unroll
    for (int c = 0; c < 6; ++c) { sh[tid][c] = s[c]; sh[tid][6 + c] = s2[c]; }
    __syncthreads();
    for (int st = 128; st > 0; st >>= 1) {
        if (tid < st) {
#pragma unroll
            for (int q = 0; q < 12; ++q) sh[tid][q] += sh[tid + st][q];
        }
        __syncthreads();
    }
    if (tid < 12) part[(size_t)blk * 12 + tid] = sh[0][tid];
}

// parallel finalizer: 192 threads = 12 stats x 16 groups
__global__ __launch_bounds__(256) void k_stats6_fin(const double* __restrict__ part, int nblk, int R,
                                                    float* __restrict__ mean, float* __restrict__ rstd) {
    __shared__ double sh[16][12];
    int t = threadIdx.x;
    if (t < 192) {
        int q = t % 12, g = t / 12;          // g < 16
        double s = 0.0;
        for (int b = g; b < nblk; b += 16) s += part[(size_t)b * 12 + q];
        sh[g][q] = s;
    }
    __syncthreads();
    if (t < 12) {
        double s = 0.0;
#pragma unroll
        for (int g = 0; g < 16; ++g) s += sh[g][t];
        sh[0][t] = s;
    }
    __syncthreads();
    if (t < 6) {
        double mu = sh[0][t] / R;
        double var = sh[0][6 + t] / R - mu * mu;
        mean[t] = (float)mu;
        rstd[t] = (float)(1.0 / sqrt(var + 1e-5));
    }
}

__global__ __launch_bounds__(256) void k_stats256_part(const float* __restrict__ v, int R, int nblk,
                                                       double* __restrict__ part) {
    int blk = blockIdx.x, c = threadIdx.x;
    int rows = R / nblk;
    int r0 = blk * rows;
    double s = 0.0, s2 = 0.0;
    for (int r = r0; r < r0 + rows; ++r) {
        double t = v[(size_t)r * Ee + c];
        s += t; s2 += t * t;
    }
    part[(size_t)blk * (2 * Ee) + c] = s;
    part[(size_t)blk * (2 * Ee) + Ee + c] = s2;
}

// 4 independent accumulators break the serial dependent-load chain
__global__ __launch_bounds__(256) void k_stats256_fin(const double* __restrict__ part, int nblk, int R,
                                                      float* __restrict__ mean, float* __restrict__ rstd) {
    int c = threadIdx.x;
    double s0 = 0.0, s1 = 0.0, s2a = 0.0, s3 = 0.0;
    double t0 = 0.0, t1 = 0.0, t2 = 0.0, t3 = 0.0;
    for (int b = 0; b < nblk; b += 4) {
        s0 += part[(size_t)b * (2 * Ee) + c];
        s1 += part[(size_t)(b + 1) * (2 * Ee) + c];
        s2a += part[(size_t)(b + 2) * (2 * Ee) + c];
        s3 += part[(size_t)(b + 3) * (2 * Ee) + c];
        t0 += part[(size_t)b * (2 * Ee) + Ee + c];
        t1 += part[(size_t)(b + 1) * (2 * Ee) + Ee + c];
        t2 += part[(size_t)(b + 2) * (2 * Ee) + Ee + c];
        t3 += part[(size_t)(b + 3) * (2 * Ee) + Ee + c];
    }
    double s = (s0 + s1) + (s2a + s3);
    double s2 = (t0 + t1) + (t2 + t3);
    double mu = s / R;
    double var = s2 / R - mu * mu;
    mean[c] = (float)mu;
    rstd[c] = (float)(1.0 / sqrt(var + 1e-5));
}

// ---------------- BN1+ELU, max over K, @W2+b2 ----------------
__global__ __launch_bounds__(256) void k_maxh2(const float* __restrict__ h1,
                                               const float* __restrict__ mean1, const float* __restrict__ rstd1,
                                               const float* __restrict__ g1, const float* __restrict__ be1,
                                               const float* __restrict__ W2, const float* __restrict__ b2,
                                               float* __restrict__ x0) {
    int bn = blockIdx.x;
    int t = threadIdx.x;
    __shared__ float hval[KK][6];
    __shared__ float hmax[6];
    if (t < KK * 6) {
        int k = t / 6, c = t % 6;
        float v = h1[((size_t)bn * KK + k) * 6 + c];
        v = (v - mean1[c]) * rstd1[c] * g1[c] + be1[c];
        hval[k][c] = eluf(v);
    }
    __syncthreads();
    if (t < 6) {
        float m = -FLT_MAX;
        for (int k = 0; k < KK; ++k) m = fmaxf(m, hval[k][t]);
        hmax[t] = m;
    }
    __syncthreads();
    float s = b2[t];
#pragma unroll
    for (int i = 0; i < 6; ++i) s += hmax[i] * W2[i * Ee + t];
    x0[(size_t)bn * Ee + t] = s;
}

// ---------------- fused BN2-apply + layer-0 LN (wave per row) ----------------
__global__ __launch_bounds__(256) void k_bnln(float* __restrict__ X,
                                              const float* __restrict__ mean2, const float* __restrict__ rstd2,
                                              const float* __restrict__ g2, const float* __restrict__ be2,
                                              const float* __restrict__ g, const float* __restrict__ b,
                                              __bf16* __restrict__ Yb) {
    int row = blockIdx.x * 4 + (threadIdx.x >> 6);
    int lane = threadIdx.x & 63;
    int c0 = lane * 4;
    float4 v = *(const float4*)(X + (size_t)row * Ee + c0);
    v.x = eluf((v.x - mean2[c0 + 0]) * rstd2[c0 + 0] * g2[c0 + 0] + be2[c0 + 0]);
    v.y = eluf((v.y - mean2[c0 + 1]) * rstd2[c0 + 1] * g2[c0 + 1] + be2[c0 + 1]);
    v.z = eluf((v.z - mean2[c0 + 2]) * rstd2[c0 + 2] * g2[c0 + 2] + be2[c0 + 2]);
    v.w = eluf((v.w - mean2[c0 + 3]) * rstd2[c0 + 3] * g2[c0 + 3] + be2[c0 + 3]);
    *(float4*)(X + (size_t)row * Ee + c0) = v;
    float s = v.x + v.y + v.z + v.w;
#pragma unroll
    for (int off = 32; off; off >>= 1) s += __shfl_xor(s, off, 64);
    float mu = s * (1.0f / Ee);
    float d0 = v.x - mu, d1 = v.y - mu, d2 = v.z - mu, d3 = v.w - mu;
    float s2 = d0 * d0 + d1 * d1 + d2 * d2 + d3 * d3;
#pragma unroll
    for (int off = 32; off; off >>= 1) s2 += __shfl_xor(s2, off, 64);
    float rstd = 1.0f / sqrtf(s2 * (1.0f / Ee) + 1e-5f);
    float4 gv = *(const float4*)(g + c0);
    float4 bv = *(const float4*)(b + c0);
    bf16x4 o;
    o[0] = (__bf16)(gv.x * d0 * rstd + bv.x);
    o[1] = (__bf16)(gv.y * d1 * rstd + bv.y);
    o[2] = (__bf16)(gv.z * d2 * rstd + bv.z);
    o[3] = (__bf16)(gv.w * d3 * rstd + bv.w);
    *(bf16x4*)(Yb + (size_t)row * Ee + c0) = o;
}

// ---------------- LayerNorm -> bf16 (one wave per row of 256) ----------------
__global__ __launch_bounds__(256) void k_lnb(const float* __restrict__ X,
                                             const float* __restrict__ g, const float* __restrict__ b,
                                             __bf16* __restrict__ Yb) {
    int row = blockIdx.x * 4 + (threadIdx.x >> 6);
    int lane = threadIdx.x & 63;
    float4 v = *(const float4*)(X + (size_t)row * Ee + lane * 4);
    float s = v.x + v.y + v.z + v.w;
#pragma unroll
    for (int off = 32; off; off >>= 1) s += __shfl_xor(s, off, 64);
    float mu = s * (1.0f / Ee);
    float d0 = v.x - mu, d1 = v.y - mu, d2 = v.z - mu, d3 = v.w - mu;
    float s2 = d0 * d0 + d1 * d1 + d2 * d2 + d3 * d3;
#pragma unroll
    for (int off = 32; off; off >>= 1) s2 += __shfl_xor(s2, off, 64);
    float rstd = 1.0f / sqrtf(s2 * (1.0f / Ee) + 1e-5f);
    float4 gv = *(const float4*)(g + lane * 4);
    float4 bv = *(const float4*)(b + lane * 4);
    bf16x4 o;
    o[0] = (__bf16)(gv.x * d0 * rstd + bv.x);
    o[1] = (__bf16)(gv.y * d1 * rstd + bv.y);
    o[2] = (__bf16)(gv.z * d2 * rstd + bv.z);
    o[3] = (__bf16)(gv.w * d3 * rstd + bv.w);
    *(bf16x4*)(Yb + (size_t)row * Ee + lane * 4) = o;
}

// ---------------- fused weight transpose + bf16 convert for all 4 weight sets ----------------
__global__ __launch_bounds__(256) void k_wtall(const float* __restrict__ attn_w, const float* __restrict__ out_w,
                                               const float* __restrict__ ff1_w, const float* __restrict__ ff2_w,
                                               __bf16* __restrict__ attn_wt, __bf16* __restrict__ out_wt,
                                               __bf16* __restrict__ ff1_wt, __bf16* __restrict__ ff2_wt) {
    int bid = blockIdx.x;
    const float* w; __bf16* wt; int K, N, n0, k0;
    if (bid < 144) {           // attn: 12 x 4 x 3
        int r = bid; int z = r / 48; r %= 48;
        K = Ee; N = QKV; n0 = (r % 12) * 64; k0 = (r / 12) * 64;
        w = attn_w + (size_t)z * K * N; wt = attn_wt + (size_t)z * K * N;
    } else if (bid < 192) {    // out: 4 x 4 x 3
        int r = bid - 144; int z = r / 16; r %= 16;
        K = Ee; N = Ee; n0 = (r % 4) * 64; k0 = (r / 4) * 64;
        w = out_w + (size_t)z * K * N; wt = out_wt + (size_t)z * K * N;
    } else if (bid < 288) {    // ff1: 8 x 4 x 3
        int r = bid - 192; int z = r / 32; r %= 32;
        K = Ee; N = FF; n0 = (r % 8) * 64; k0 = (r / 8) * 64;
        w = ff1_w + (size_t)z * K * N; wt = ff1_wt + (size_t)z * K * N;
    } else {                   // ff2: 4 x 8 x 3
        int r = bid - 288; int z = r / 32; r %= 32;
        K = FF; N = Ee; n0 = (r % 4) * 64; k0 = (r / 4) * 64;
        w = ff2_w + (size_t)z * K * N; wt = ff2_wt + (size_t)z * K * N;
    }
    __shared__ float L[64][65];
    int t = threadIdx.x;
    int r = t >> 4, c4 = (t & 15) * 4;
#pragma unroll
    for (int j = 0; j < 4; ++j) {
        float4 v = *(const float4*)(w + (size_t)(k0 + r + j * 16) * N + n0 + c4);
        L[r + j * 16][c4 + 0] = v.x; L[r + j * 16][c4 + 1] = v.y;
        L[r + j * 16][c4 + 2] = v.z; L[r + j * 16][c4 + 3] = v.w;
    }
    __syncthreads();
#pragma unroll
    for (int j = 0; j < 4; ++j) {
        int nn = r + j * 16;
        bf16x4 o;
        o[0] = (__bf16)L[c4 + 0][nn]; o[1] = (__bf16)L[c4 + 1][nn];
        o[2] = (__bf16)L[c4 + 2][nn]; o[3] = (__bf16)L[c4 + 3][nn];
        *(bf16x4*)(wt + (size_t)(n0 + nn) * K + k0 + c4) = o;
    }
}

// ---------------- bf16 MFMA GEMM, 64x128 tile ----------------
// OUTM: 0=f32 1=bf16 ; RESM: 0=none 1=bf16 2=f32 ; ACT: 0=none 1=gelu
// QKVM=1: q-cols (<Ee) scaled by CEXP -> qkvb; K-cols -> kp[b][h][key][d] (per-head packed);
//         V-cols -> vt[b][h][key/32][d][key%32]; K/V NOT written to qkvb (attn reads Kp/Vt).
template<int OUTM, int RESM, int ACT, int QKVM>
__global__ __launch_bounds__(256) void k_mgemm(const __bf16* __restrict__ Ain,
                                               const __bf16* __restrict__ Wt,
                                               const float* __restrict__ bias,
                                               const void* __restrict__ res,
                                               void* __restrict__ out,
                                               int Kd, int Nd,
                                               __bf16* __restrict__ kp,
                                               __bf16* __restrict__ vt) {
    __shared__ __bf16 As[64 * 32];
    __shared__ __bf16 Bs[128 * 32];
    int tid = threadIdx.x;
    int n0 = blockIdx.x * 128, m0 = blockIdx.y * 64;
    int wave = tid >> 6, lane = tid & 63;
    int wr = wave >> 1, wc = wave & 1;      // wave rows: wr*32, cols: wc*64
    int t = lane & 15, gg = lane >> 4;
    f32x4 acc[2][4];
#pragma unroll
    for (int m = 0; m < 2; ++m)
#pragma unroll
        for (int nn = 0; nn < 4; ++nn) acc[m][nn] = (f32x4){0.f, 0.f, 0.f, 0.f};
    int r0 = tid >> 2, g0 = tid & 3;        // rows 0..63, 8-col groups
    for (int kt = 0; kt < Kd; kt += 32) {
#if HAVE_GLOAD_LDS
        __syncthreads();          // prior iteration's frag reads complete before overwrite
        gl_lds16(Ain + (size_t)(m0 + r0) * Kd + kt + g0 * 8, &As[r0 * 32 + g0 * 8]);
        gl_lds16(Wt + (size_t)(n0 + r0) * Kd + kt + g0 * 8, &Bs[r0 * 32 + g0 * 8]);
        gl_lds16(Wt + (size_t)(n0 + 64 + r0) * Kd + kt + g0 * 8, &Bs[(64 + r0) * 32 + g0 * 8]);
        __syncthreads();          // drains vmcnt: LDS tiles ready
#else
        bf16x8 a0 = *(const bf16x8*)(Ain + (size_t)(m0 + r0) * Kd + kt + g0 * 8);
        bf16x8 w0 = *(const bf16x8*)(Wt + (size_t)(n0 + r0) * Kd + kt + g0 * 8);
        bf16x8 w1 = *(const bf16x8*)(Wt + (size_t)(n0 + 64 + r0) * Kd + kt + g0 * 8);
        __syncthreads();
        *(bf16x8*)&As[r0 * 32 + g0 * 8] = a0;
        *(bf16x8*)&Bs[r0 * 32 + g0 * 8] = w0;
        *(bf16x8*)&Bs[(64 + r0) * 32 + g0 * 8] = w1;
        __syncthreads();
#endif
        bf16x8 af[2], bfr[4];
#pragma unroll
        for (int m = 0; m < 2; ++m) af[m] = *(const bf16x8*)&As[(wr * 32 + m * 16 + t) * 32 + gg * 8];
#pragma unroll
        for (int nn = 0; nn < 4; ++nn) bfr[nn] = *(const bf16x8*)&Bs[(wc * 64 + nn * 16 + t) * 32 + gg * 8];
#pragma unroll
        for (int m = 0; m < 2; ++m)
#pragma unroll
            for (int nn = 0; nn < 4; ++nn)
                acc[m][nn] = __builtin_amdgcn_mfma_f32_16x16x32_bf16(af[m], bfr[nn], acc[m][nn], 0, 0, 0);
    }
#pragma unroll
    for (int m = 0; m < 2; ++m) {
#pragma unroll
        for (int nn = 0; nn < 4; ++nn) {
            int ocol = n0 + wc * 64 + nn * 16 + t;
            float bv = bias[ocol];
            float vv[4];
#pragma unroll
            for (int j = 0; j < 4; ++j) {
                int orow = m0 + wr * 32 + m * 16 + gg * 4 + j;
                float v = acc[m][nn][j] + bv;
                if (RESM == 1) v += (float)((const __bf16*)res)[(size_t)orow * Nd + ocol];
                if (RESM == 2) v += ((const float*)res)[(size_t)orow * Nd + ocol];
                if (ACT == 1) v = geluf(v);
                if (QKVM == 1 && ocol < Ee) v *= CEXP;   // pre-scale q for attn exp2
                vv[j] = v;
                if (!(QKVM == 1 && ocol >= Ee)) {        // K/V skip qkvb; go to Kp/Vt instead
                    if (OUTM == 0) ((float*)out)[(size_t)orow * Nd + ocol] = v;
                    else           ((__bf16*)out)[(size_t)orow * Nd + ocol] = (__bf16)v;
                }
            }
            if (QKVM == 1 && ocol >= Ee && ocol < 2 * Ee) {   // per-head packed K store
                int d = ocol - Ee;
                int h = d >> 5, dd = d & 31;
                int orow0 = m0 + wr * 32 + m * 16 + gg * 4;
                int bi = orow0 >> 11, n = orow0 & (Nn - 1);
                __bf16* kb = kp + (((size_t)(bi * Hh + h) * Nn + n) * DH + dd);
                kb[0] = (__bf16)vv[0]; kb[DH] = (__bf16)vv[1];
                kb[2 * DH] = (__bf16)vv[2]; kb[3 * DH] = (__bf16)vv[3];
            }
            if (QKVM == 1 && ocol >= 2 * Ee) {           // blocked-transpose V store
                int d = ocol - 2 * Ee;
                int h = d >> 5, dd = d & 31;
                int orow0 = m0 + wr * 32 + m * 16 + gg * 4;
                int bi = orow0 >> 11, n = orow0 & (Nn - 1);
                int kc = n >> 5, k5 = n & 31;
                bf16x4 o;
                o[0] = (__bf16)vv[0]; o[1] = (__bf16)vv[1];
                o[2] = (__bf16)vv[2]; o[3] = (__bf16)vv[3];
                *(bf16x4*)(vt + ((((size_t)(bi * Hh + h) * (Nn / 32) + kc) * DH + dd) << 5) + k5) = o;
            }
        }
    }
}

// ---------------- swapped-operand 32x32 MFMA flash attention: no LDS, no barriers ----------------
// Q (pre-scaled) from qkvb; K from per-head packed Kp; V from 32-key-blocked Vt.
__global__ __launch_bounds__(256) void k_attn(const __bf16* __restrict__ qkv,
                                              const __bf16* __restrict__ kp,
                                              const __bf16* __restrict__ vt,
                                              __bf16* __restrict__ obf) {
    int wgid = (blockIdx.x & 7) * 128 + (blockIdx.x >> 3);   // 1024 blocks, bijective
    int qg = wgid & 15;
    int bh = wgid >> 4;
    int h = bh & 7, b = bh >> 3;
    int wave = threadIdx.x >> 6, lane = threadIdx.x & 63;
    int l31 = lane & 31, hi = lane >> 5;
    int qb = qg * 128 + wave * 32;
    const size_t base = (size_t)b * Nn * QKV;

    const __bf16* qrow = qkv + base + (size_t)(qb + l31) * QKV + h * DH;
    bf16x8 qf0 = *(const bf16x8*)(qrow + hi * 8);
    bf16x8 qf1 = *(const bf16x8*)(qrow + 16 + hi * 8);

    const __bf16* kpb = kp + ((size_t)(b * Hh + h) * Nn + l31) * DH + hi * 8;   // + c0*DH per chunk
    const __bf16* vtb = vt + ((size_t)(b * Hh + h) * (Nn / 32)) * DH * 32 + l31 * 32 + hi * 8;

    f32x16 oacc = {0.f,0.f,0.f,0.f,0.f,0.f,0.f,0.f,0.f,0.f,0.f,0.f,0.f,0.f,0.f,0.f};
    float lsum = 0.0f;

    for (int c0 = 0; c0 < Nn; c0 += 32) {
        const __bf16* kr = kpb + (size_t)c0 * DH;
        bf16x8 kf0 = *(const bf16x8*)kr;           // K[c0+l31][d=hi*8..]
        bf16x8 kf1 = *(const bf16x8*)(kr + 16);    // K[c0+l31][d=16+hi*8..]

        f32x16 s = {0.f,0.f,0.f,0.f,0.f,0.f,0.f,0.f,0.f,0.f,0.f,0.f,0.f,0.f,0.f,0.f};
        s = __builtin_amdgcn_mfma_f32_32x32x16_bf16(kf0, qf0, s, 0, 0, 0);
        s = __builtin_amdgcn_mfma_f32_32x32x16_bf16(kf1, qf1, s, 0, 0, 0);
        // lane holds S^T[key=(reg&3)+8*(reg>>2)+4*hi][q=l31], already in log2 units

        float p[16];
#pragma unroll
        for (int i = 0; i < 16; ++i) p[i] = EXP2(s[i]);
        float s0 = (p[0] + p[1]) + (p[2] + p[3]);
        float s1 = (p[4] + p[5]) + (p[6] + p[7]);
        float s2r = (p[8] + p[9]) + (p[10] + p[11]);
        float s3 = (p[12] + p[13]) + (p[14] + p[15]);
        lsum += (s0 + s1) + (s2r + s3);

        unsigned d0 = pkbf(p[0], p[1]),  d1 = pkbf(p[2], p[3]);
        unsigned d2 = pkbf(p[4], p[5]),  d3 = pkbf(p[6], p[7]);
        unsigned d4 = pkbf(p[8], p[9]),  d5 = pkbf(p[10], p[11]);
        unsigned d6 = pkbf(p[12], p[13]), d7 = pkbf(p[14], p[15]);
        unsigned w0a, w0b, w1a, w1b, w2a, w2b, w3a, w3b;
        swap32(d2, d0, w2a, w0a, hi);
        swap32(d3, d1, w3a, w1a, hi);
        swap32(d6, d4, w2b, w0b, hi);
        swap32(d7, d5, w3b, w1b, hi);
        union { unsigned u[4]; bf16x8 v; } pa0, pa1;
        pa0.u[0] = w0a; pa0.u[1] = w1a; pa0.u[2] = w2a; pa0.u[3] = w3a;
        pa1.u[0] = w0b; pa1.u[1] = w1b; pa1.u[2] = w2b; pa1.u[3] = w3b;

        const __bf16* vp = vtb + (size_t)(c0 >> 5) * (DH * 32);
        bf16x8 vf0 = *(const bf16x8*)vp;           // V[key=hi*8+j][d=l31]
        bf16x8 vf1 = *(const bf16x8*)(vp + 16);    // V[key=16+hi*8+j][d=l31]

        oacc = __builtin_amdgcn_mfma_f32_32x32x16_bf16(pa0.v, vf0, oacc, 0, 0, 0);
        oacc = __builtin_amdgcn_mfma_f32_32x32x16_bf16(pa1.v, vf1, oacc, 0, 0, 0);
    }

    float ltot = lsum + __shfl_xor(lsum, 32, 64);
    float invl = 1.0f / ltot;     // valid for q = l31
#pragma unroll
    for (int reg = 0; reg < 16; ++reg) {
        int row = (reg & 3) + 8 * (reg >> 2) + 4 * hi;
        float iv = __shfl(invl, row, 64);
        obf[((size_t)(b * Nn + qb + row)) * Ee + h * DH + l31] = (__bf16)(oacc[reg] * iv);
    }
}

// ---------------- decoder ----------------
// 256 blocks (32 chunks x 8 b), 4-acc ILP
__global__ __launch_bounds__(256) void k_meanpart(const float* __restrict__ X, float* __restrict__ pm) {
    int chunk = blockIdx.x, b = blockIdx.y;
    int e = threadIdx.x;
    int n0 = chunk * 64;
    float s0 = 0.f, s1 = 0.f, s2 = 0.f, s3 = 0.f;
    for (int n = n0; n < n0 + 64; n += 4) {
        s0 += X[((size_t)b * Nn + n) * Ee + e];
        s1 += X[((size_t)b * Nn + n + 1) * Ee + e];
        s2 += X[((size_t)b * Nn + n + 2) * Ee + e];
        s3 += X[((size_t)b * Nn + n + 3) * Ee + e];
    }
    pm[(size_t)(b * 32 + chunk) * Ee + e] = (s0 + s1) + (s2 + s3);
}
// fused mean-finalize + dec1 (one block per b; mvec in LDS)
__global__ __launch_bounds__(512) void k_dec1f(const float* __restrict__ pm,
                                               const float* __restrict__ w,
                                               const float* __restrict__ bias,
                                               float* __restrict__ t1) {
    __shared__ float mv[Ee];
    int b = blockIdx.x, t = threadIdx.x;
    if (t < Ee) {
        float s0 = 0.f, s1 = 0.f, s2 = 0.f, s3 = 0.f;
        for (int c = 0; c < 32; c += 4) {
            s0 += pm[(size_t)(b * 32 + c) * Ee + t];
            s1 += pm[(size_t)(b * 32 + c + 1) * Ee + t];
            s2 += pm[(size_t)(b * 32 + c + 2) * Ee + t];
            s3 += pm[(size_t)(b * 32 + c + 3) * Ee + t];
        }
        mv[t] = ((s0 + s1) + (s2 + s3)) * (1.0f / Nn);
    }
    __syncthreads();
    float a0 = 0.f, a1 = 0.f, a2 = 0.f, a3 = 0.f;
    for (int i = 0; i < Ee; i += 4) {
        a0 += mv[i] * w[i * FF + t];
        a1 += mv[i + 1] * w[(i + 1) * FF + t];
        a2 += mv[i + 2] * w[(i + 2) * FF + t];
        a3 += mv[i + 3] * w[(i + 3) * FF + t];
    }
    t1[b * FF + t] = geluf(bias[t] + (a0 + a1) + (a2 + a3));
}
__global__ __launch_bounds__(256) void k_dec2(const float* __restrict__ t1, const float* __restrict__ w,
                                              const float* __restrict__ bias, float* __restrict__ out) {
    int i = blockIdx.x * 256 + threadIdx.x;
    int b = i / 3072, j = i % 3072;
    float a0 = 0.f, a1 = 0.f, a2 = 0.f, a3 = 0.f;
    for (int k = 0; k < FF; k += 4) {
        a0 += t1[b * FF + k] * w[k * 3072 + j];
        a1 += t1[b * FF + k + 1] * w[(k + 1) * 3072 + j];
        a2 += t1[b * FF + k + 2] * w[(k + 2) * 3072 + j];
        a3 += t1[b * FF + k + 3] * w[(k + 3) * 3072 + j];
    }
    out[i] = bias[j] + (a0 + a1) + (a2 + a3);
}

extern "C" void kernel_launch(void* const* d_in, const int* in_sizes, int n_in,
                              void* d_out, int out_size, void* d_ws, size_t ws_size,
                              hipStream_t stream) {
    const float* x      = (const float*)d_in[0];
    const float* W1     = (const float*)d_in[1];
    const float* b1     = (const float*)d_in[2];
    const float* g1     = (const float*)d_in[3];
    const float* be1    = (const float*)d_in[4];
    const float* W2     = (const float*)d_in[5];
    const float* b2     = (const float*)d_in[6];
    const float* g2     = (const float*)d_in[7];
    const float* be2    = (const float*)d_in[8];
    const float* ln1_g  = (const float*)d_in[9];
    const float* ln1_b  = (const float*)d_in[10];
    const float* attn_w = (const float*)d_in[11];
    const float* attn_b = (const float*)d_in[12];
    const float* out_w  = (const float*)d_in[13];
    const float* out_b  = (const float*)d_in[14];
    const float* ln2_g  = (const float*)d_in[15];
    const float* ln2_b  = (const float*)d_in[16];
    const float* ff1_w  = (const float*)d_in[17];
    const float* ff1_b  = (const float*)d_in[18];
    const float* ff2_w  = (const float*)d_in[19];
    const float* ff2_b  = (const float*)d_in[20];
    const float* dec1_w = (const float*)d_in[21];
    const float* dec1_b = (const float*)d_in[22];
    const float* dec2_w = (const float*)d_in[23];
    const float* dec2_b = (const float*)d_in[24];
    (void)in_sizes; (void)n_in; (void)out_size; (void)ws_size;

    const size_t MN = (size_t)Bb * Nn * Ee;            // 16384*256

    float*  A    = (float*)d_ws;                       // xcur fp32
    __bf16* Ab   = (__bf16*)(A + MN);                  // hn bf16
    __bf16* qkvb = Ab + MN;                            // qkv bf16 (only q-cols written in steady state)
    __bf16* obf  = qkvb + (size_t)Bb * Nn * QKV;       // attn out bf16
    __bf16* ffb  = obf + MN;                           // ff intermediate bf16 (aliases Kp+Vt)
    __bf16* attn_wt = ffb + (size_t)Bb * Nn * FF;      // transposed bf16 weights
    __bf16* out_wt  = attn_wt + (size_t)NB * QKV * Ee;
    __bf16* ff1_wt  = out_wt + (size_t)NB * Ee * Ee;
    __bf16* ff2_wt  = ff1_wt + (size_t)NB * FF * Ee;
    float*  S       = (float*)(ff2_wt + (size_t)NB * Ee * FF);

    // Kp[b][h][key][d] and Vt32[b][h][key/32][d][key%32] alias ffb
    __bf16* Vt = ffb;
    __bf16* Kp = ffb + (size_t)Bb * Hh * Nn * DH;

    float* mean1 = S,      *rstd1 = S + 16;
    float* mean2 = S + 32, *rstd2 = S + 32 + Ee;
    double* part6   = (double*)(S + 32768);            // 512*12 doubles
    double* part256 = part6 + 512 * 12;                // 64*512 doubles (ends ~ S+110592 floats)
    float* pm    = S + 131072;                         // [8*32][256] = 65536 floats
    float* t1    = pm + 65536;                         // [8][512]

    // ARPE scratch aliases qkvb (dead until first qkv GEMM)
    int*   idx = (int*)qkvb;
    float* h1  = (float*)(idx + (size_t)Bb * Nn * KK);

    // fused weight convert+transpose (independent of ARPE)
    k_wtall<<<384, 256, 0, stream>>>(attn_w, out_w, ff1_w, ff2_w,
                                     attn_wt, out_wt, ff1_wt, ff2_wt);

    k_knn <<<Bb * Nn / 4, 256, 0, stream>>>(x, idx);
    k_h1  <<<(Bb * Nn * KK) / 256, 256, 0, stream>>>(x, idx, W1, b1, h1);
    k_stats6_part<<<512, 256, 0, stream>>>(h1, Bb * Nn * KK, 512, part6);
    k_stats6_fin<<<1, 256, 0, stream>>>(part6, 512, Bb * Nn * KK, mean1, rstd1);
    k_maxh2<<<Bb * Nn, 256, 0, stream>>>(h1, mean1, rstd1, g1, be1, W2, b2, A);
    k_stats256_part<<<64, 256, 0, stream>>>(A, Bb * Nn, 64, part256);
    k_stats256_fin<<<1, 256, 0, stream>>>(part256, 64, Bb * Nn, mean2, rstd2);
    // fused BN2-apply + layer-0 LN
    k_bnln<<<Bb * Nn / 4, 256, 0, stream>>>(A, mean2, rstd2, g2, be2, ln1_g, ln1_b, Ab);

    const int M = Bb * Nn;
    for (int i = 0; i < NB; ++i) {
        if (i > 0)
            k_lnb<<<M / 4, 256, 0, stream>>>(A, ln1_g + i * Ee, ln1_b + i * Ee, Ab);
        k_mgemm<1, 0, 0, 1><<<dim3(QKV / 128, M / 64), 256, 0, stream>>>(
            Ab, attn_wt + (size_t)i * QKV * Ee, attn_b + i * QKV, nullptr, qkvb, Ee, QKV, Kp, Vt);
        k_attn<<<Bb * Hh * 16, 256, 0, stream>>>(qkvb, Kp, Vt, obf);
        k_mgemm<0, 1, 0, 0><<<dim3(Ee / 128, M / 64), 256, 0, stream>>>(
            obf, out_wt + (size_t)i * Ee * Ee, out_b + i * Ee, Ab, A, Ee, Ee, nullptr, nullptr);
        k_lnb<<<M / 4, 256, 0, stream>>>(A, ln2_g + i * Ee, ln2_b + i * Ee, Ab);
        k_mgemm<1, 0, 1, 0><<<dim3(FF / 128, M / 64), 256, 0, stream>>>(
            Ab, ff1_wt + (size_t)i * FF * Ee, ff1_b + i * FF, nullptr, ffb, Ee, FF, nullptr, nullptr);
        k_mgemm<0, 2, 0, 0><<<dim3(Ee / 128, M / 64), 256, 0, stream>>>(
            ffb, ff2_wt + (size_t)i * Ee * FF, ff2_b + i * Ee, A, A, FF, Ee, nullptr, nullptr);
    }

    k_meanpart<<<dim3(32, Bb), 256, 0, stream>>>(A, pm);
    k_dec1f<<<Bb, FF, 0, stream>>>(pm, dec1_w, dec1_b, t1);
    k_dec2<<<(Bb * OUTPTS * 3) / 256, 256, 0, stream>>>(t1, dec2_w, dec2_b, (float*)d_out);
}